// Round 10
// baseline (307.903 us; speedup 1.0000x reference)
//
#include <hip/hip_runtime.h>
#include <hip/hip_bf16.h>

// ============================================================================
// Round 10: fix latency-bound fp64 dot loops (r9: ntmout_conv2 67us at 20
// VGPRs -> zero load pipelining, one L2 stall per d-iteration; same pattern
// in lstm and rowsum). (a) 8-way manual unroll w/ independent accumulators
// (8-24 loads in flight); (b) rowsum 3 blocks -> 24 partial blocks (r x 8
// d-chunks), partials combined in ntmout. Reduction regrouping only
// (~1e-15 deltas vs 3.8e-6 ref-noise floor). Convs unchanged from r9.
// ============================================================================

typedef __attribute__((ext_vector_type(8))) short short8;
typedef __attribute__((ext_vector_type(4))) float f32x4;

// ---- workspace layout (bytes) ----
static const size_t OFF_A1H = 0;                       // A1/A4 NHWC hi (B,34,34,64)
static const size_t OFF_A1L = 9469952;                 // -> end 18,939,904
static const size_t OFF_T1  = 18939904;                // t1 conv1 out NCHW f32 16MB
static const size_t OFF_A3H = 39911424;                // conv3 input NHWC (B,18,18,64)
static const size_t OFF_A3L = 42565632;                // -> end 45,219,840
static const size_t OFF_W1  = 45219840;                // packed whi+wlo 147,456 B/layer
static const size_t OFF_W3  = 45367296;
static const size_t OFF_W4  = 45514752;
static const size_t OFF_XE  = 45662208;                // xE (64,256) f32
static const size_t OFF_H   = 45727744;                // h  (64,256) f32
static const size_t OFF_RV  = 45793280;                // rv (64,3) f64
static const size_t OFF_RS  = 45794816;                // rs_part (24,256) f64 49,152B

__device__ inline void bf16split(float v, unsigned short& h, unsigned short& l) {
    __hip_bfloat16 hb = __float2bfloat16(v);
    float hf = __bfloat162float(hb);
    __hip_bfloat16 lb = __float2bfloat16(v - hf);
    h = __builtin_bit_cast(unsigned short, hb);
    l = __builtin_bit_cast(unsigned short, lb);
}

// ---- weight prep, all 3 layers: (co,ci,3,3) f32 -> fragment-packed hi/lo ----
__global__ void wprep_all_kernel(
    const float* __restrict__ w1, const float* __restrict__ w3,
    const float* __restrict__ w4,
    unsigned short* __restrict__ whi1, unsigned short* __restrict__ wlo1,
    unsigned short* __restrict__ whi3, unsigned short* __restrict__ wlo3,
    unsigned short* __restrict__ whi4, unsigned short* __restrict__ wlo4)
{
    int layer = blockIdx.x / 144;
    int r = (blockIdx.x % 144) * 256 + threadIdx.x;    // < 36864
    const float* w = layer == 0 ? w1 : (layer == 1 ? w3 : w4);
    unsigned short* hi = layer == 0 ? whi1 : (layer == 1 ? whi3 : whi4);
    unsigned short* lo = layer == 0 ? wlo1 : (layer == 1 ? wlo3 : wlo4);
    int j  = r & 7;
    int ln = (r >> 3) & 63;
    int n  = (r >> 9) & 3;
    int ch = (r >> 11) & 1;
    int t  = r >> 12;
    int lc = ln & 15, kg = ln >> 4;
    int co = n * 16 + lc;
    int ci = ch * 32 + kg * 8 + j;
    unsigned short h, l;
    bf16split(w[(co * 64 + ci) * 9 + t], h, l);
    hi[r] = h; lo[r] = l;
}

// ---- zero halo rings of a1 (S=32) and a3 (S=16) in one kernel ----
__device__ inline void halo_zero_one(unsigned short* hi, unsigned short* lo,
                                     int S, int idx)
{
    int P = S + 2, ring = 4 * S + 4;
    int co = idx & 63;
    int cell = (idx >> 6) % ring;
    int b = (idx >> 6) / ring;
    int y, x;
    if (cell < P)            { y = 0;     x = cell; }
    else if (cell < 2 * P)   { y = P - 1; x = cell - P; }
    else { int c2 = cell - 2 * P; y = 1 + (c2 >> 1); x = (c2 & 1) ? P - 1 : 0; }
    size_t a = ((size_t)(b * P + y) * P + x) * 64 + co;
    hi[a] = 0; lo[a] = 0;
}

__global__ void halo_all_kernel(unsigned short* __restrict__ a1h,
                                unsigned short* __restrict__ a1l,
                                unsigned short* __restrict__ a3h,
                                unsigned short* __restrict__ a3l)
{
    int idx = blockIdx.x * 256 + threadIdx.x;          // 819,200 total
    if (idx < 540672) halo_zero_one(a1h, a1l, 32, idx);
    else              halo_zero_one(a3h, a3l, 16, idx - 540672);
}

// ---- fused conv0 (1->64, 3x3 SAME, relu) + avgpool2 -> A1 NHWC hi/lo ----
__global__ __launch_bounds__(256) void conv0_pool_kernel(
    const float* __restrict__ in, const float* __restrict__ w,
    const float* __restrict__ bias,
    unsigned short* __restrict__ ohi, unsigned short* __restrict__ olo)
{
    int idx = blockIdx.x * 256 + threadIdx.x;          // 4,194,304
    int co = idx & 63, x = (idx >> 6) & 31, y = (idx >> 11) & 31, b = idx >> 16;
    float w9[9];
#pragma unroll
    for (int t = 0; t < 9; ++t) w9[t] = w[co * 9 + t];
    float bv = bias[co];
    const float* ip = in + (size_t)b * 4096;
    float p[4][4];
#pragma unroll
    for (int r = 0; r < 4; ++r) {
        int gy = 2 * y - 1 + r;
#pragma unroll
        for (int c = 0; c < 4; ++c) {
            int gx = 2 * x - 1 + c;
            float v = 0.f;
            if ((unsigned)gy < 64u && (unsigned)gx < 64u) v = ip[gy * 64 + gx];
            p[r][c] = v;
        }
    }
    float s4 = 0.f;
#pragma unroll
    for (int dy = 0; dy < 2; ++dy)
#pragma unroll
        for (int dx = 0; dx < 2; ++dx) {
            float a = bv;
#pragma unroll
            for (int ky = 0; ky < 3; ++ky)
#pragma unroll
                for (int kx = 0; kx < 3; ++kx)
                    a = fmaf(w9[ky * 3 + kx], p[dy + ky][dx + kx], a);
            s4 += fmaxf(a, 0.f);
        }
    unsigned short h, l;
    bf16split(s4 * 0.25f, h, l);
    size_t a = ((size_t)(b * 34 + y + 1) * 34 + x + 1) * 64 + co;
    ohi[a] = h; olo[a] = l;
}

// ---- MFMA implicit-GEMM conv body: 256 thr / 4 waves, ROWS rows per wave ----
template <int UP, int H, int ROWS, bool NHWC_OUT>
__device__ __forceinline__ void conv_mfma_body(
    const unsigned short* __restrict__ ahi, const unsigned short* __restrict__ alo,
    const unsigned short* __restrict__ whiP, const unsigned short* __restrict__ wloP,
    const float* __restrict__ bias,
    float* __restrict__ outf, unsigned short* __restrict__ ohi,
    unsigned short* __restrict__ olo)
{
    constexpr int TILEH = 4 * ROWS;
    constexpr int SRC   = H >> UP;
    constexpr int PITCH = SRC + 2;
    constexpr int TPR   = H / 16;
    constexpr int TPC   = H / TILEH;
    constexpr int AH    = (UP ? TILEH / 2 : TILEH) + 2;
    constexpr int AW    = UP ? 10 : 18;
    constexpr int NPX   = AH * AW;

    int b  = blockIdx.x / (TPC * TPR);
    int tt = blockIdx.x % (TPC * TPR);
    int y0 = (tt / TPR) * TILEH, x0 = (tt % TPR) * 16;
    const int tid = threadIdx.x;
    const int wv = tid >> 6, lane = tid & 63;
    const int lc = lane & 15, kg = lane >> 4;

    __shared__ unsigned short sAhi[NPX * 64];
    __shared__ unsigned short sAlo[NPX * 64];
    __shared__ unsigned short sW[2][4096];             // [buf][hi 2048 | lo 2048]

    const int r0 = ((y0 - 1) >> UP) + 1;
    const int c0 = ((x0 - 1) >> UP) + 1;

    for (int c = tid; c < NPX * 8; c += 256) {
        int pix = c >> 3, sub = c & 7;
        int py = pix / AW, px = pix - py * AW;
        size_t g = ((size_t)(b * PITCH + r0 + py) * PITCH + (c0 + px)) * 64 + sub * 8;
        int l = (pix * 64 + sub * 8) ^ ((pix & 7) << 3);
        *(short8*)&sAhi[l] = *(const short8*)&ahi[g];
        *(short8*)&sAlo[l] = *(const short8*)&alo[g];
    }
    for (int c = tid; c < 512; c += 256) {
        if (c < 256) *(short8*)&sW[0][c * 8] = *(const short8*)&whiP[c * 8];
        else *(short8*)&sW[0][2048 + (c - 256) * 8] = *(const short8*)&wloP[(c - 256) * 8];
    }
    __syncthreads();

    int lxv[3], lyv[ROWS + 2];
#pragma unroll
    for (int kx = 0; kx < 3; ++kx)
        lxv[kx] = (((x0 + lc + kx - 1) >> UP) + 1) - c0;
#pragma unroll
    for (int r = 0; r < ROWS + 2; ++r)
        lyv[r] = (((y0 + ROWS * wv + r - 1) >> UP) + 1) - r0;

    f32x4 acc[ROWS][4];
#pragma unroll
    for (int m = 0; m < ROWS; ++m)
#pragma unroll
        for (int n = 0; n < 4; ++n) acc[m][n] = f32x4{0.f, 0.f, 0.f, 0.f};

#pragma unroll
    for (int k = 0; k < 18; ++k) {                     // k = t*2 + ch
        if (k + 1 < 18) {                              // prefetch next W slice
            int slb = (k + 1) * 2048;
            for (int c = tid; c < 512; c += 256) {
                if (c < 256) *(short8*)&sW[(k + 1) & 1][c * 8] =
                    *(const short8*)&whiP[slb + c * 8];
                else *(short8*)&sW[(k + 1) & 1][2048 + (c - 256) * 8] =
                    *(const short8*)&wloP[slb + (c - 256) * 8];
            }
        }
        const int t = k >> 1, ch = k & 1;
        const int ky = t / 3, kx = t - ky * 3;
        short8 ah[ROWS], al[ROWS];
#pragma unroll
        for (int m = 0; m < ROWS; ++m) {
            int p = lyv[ky + m] * AW + lxv[kx];
            int i = (p * 64 + ch * 32 + kg * 8) ^ ((p & 7) << 3);
            ah[m] = *(const short8*)&sAhi[i];
            al[m] = *(const short8*)&sAlo[i];
        }
        const unsigned short* wb = &sW[k & 1][0];
#pragma unroll
        for (int n = 0; n < 4; ++n) {
            short8 bh = *(const short8*)&wb[(n * 64 + lane) * 8];
            short8 bl = *(const short8*)&wb[2048 + (n * 64 + lane) * 8];
#pragma unroll
            for (int m = 0; m < ROWS; ++m) {
                acc[m][n] = __builtin_amdgcn_mfma_f32_16x16x32_bf16(ah[m], bh, acc[m][n], 0, 0, 0);
                acc[m][n] = __builtin_amdgcn_mfma_f32_16x16x32_bf16(ah[m], bl, acc[m][n], 0, 0, 0);
                acc[m][n] = __builtin_amdgcn_mfma_f32_16x16x32_bf16(al[m], bh, acc[m][n], 0, 0, 0);
            }
        }
        __syncthreads();
    }

    if (NHWC_OUT) {
        const int opitch = H + 2;
#pragma unroll
        for (int n = 0; n < 4; ++n) {
            int co = n * 16 + lc;
            float bv = bias[co];
#pragma unroll
            for (int m = 0; m < ROWS; ++m) {
                int row = y0 + ROWS * wv + m, cb = x0 + kg * 4;
                f32x4 v = acc[m][n];
#pragma unroll
                for (int j = 0; j < 4; ++j) {
                    float val = fmaxf(v[j] + bv, 0.f);
                    unsigned short h, l;
                    bf16split(val, h, l);
                    size_t a = ((size_t)(b * opitch + row + 1) * opitch + cb + j + 1) * 64 + co;
                    ohi[a] = h; olo[a] = l;
                }
            }
        }
    } else {
#pragma unroll
        for (int n = 0; n < 4; ++n) {
            int co = n * 16 + lc;
            float bv = bias[co];
#pragma unroll
            for (int m = 0; m < ROWS; ++m) {
                int row = y0 + ROWS * wv + m, cb = x0 + kg * 4;
                f32x4 v = acc[m][n], res;
                res.x = fmaxf(v.x + bv, 0.f);
                res.y = fmaxf(v.y + bv, 0.f);
                res.z = fmaxf(v.z + bv, 0.f);
                res.w = fmaxf(v.w + bv, 0.f);
                *(f32x4*)&outf[((size_t)(b * 64 + co) * H + row) * H + cb] = res;
            }
        }
    }
}

__global__ __launch_bounds__(256, 2) void conv1_mfma_kernel(
    const unsigned short* __restrict__ ahi, const unsigned short* __restrict__ alo,
    const unsigned short* __restrict__ whiP, const unsigned short* __restrict__ wloP,
    const float* __restrict__ bias, float* __restrict__ outf)
{ conv_mfma_body<0, 32, 2, false>(ahi, alo, whiP, wloP, bias, outf, nullptr, nullptr); }

__global__ __launch_bounds__(256, 3) void conv3_mfma_kernel(
    const unsigned short* __restrict__ ahi, const unsigned short* __restrict__ alo,
    const unsigned short* __restrict__ whiP, const unsigned short* __restrict__ wloP,
    const float* __restrict__ bias,
    unsigned short* __restrict__ ohi, unsigned short* __restrict__ olo)
{ conv_mfma_body<1, 32, 2, true>(ahi, alo, whiP, wloP, bias, nullptr, ohi, olo); }

__global__ __launch_bounds__(256, 3) void conv4_mfma_kernel(
    const unsigned short* __restrict__ ahi, const unsigned short* __restrict__ alo,
    const unsigned short* __restrict__ whiP, const unsigned short* __restrict__ wloP,
    const float* __restrict__ bias, float* __restrict__ outf)
{ conv_mfma_body<1, 64, 4, false>(ahi, alo, whiP, wloP, bias, outf, nullptr, nullptr); }

// ---- fused avgpool2 + enc conv: t1 (64,64,32,32) -> xE (64,256) ----
__global__ __launch_bounds__(256) void pool_enc_kernel(
    const float* __restrict__ t1, const float* __restrict__ w,
    const float* __restrict__ bias, float* __restrict__ xout)
{
    int b = blockIdx.x; int tid = threadIdx.x;
    __shared__ float sE[16384];                        // pooled (64,16,16)
    for (int p = tid; p < 16384; p += 256) {
        int ch = p >> 8, y = (p >> 4) & 15, x = p & 15;
        const float* ip = t1 + ((size_t)(b * 64 + ch) * 32 + 2 * y) * 32 + 2 * x;
        sE[p] = (ip[0] + ip[1] + ip[32] + ip[33]) * 0.25f;
    }
    __syncthreads();
    int y = tid >> 4, x = tid & 15;
    double acc = 0.0;
    for (int ci = 0; ci < 64; ++ci) {
#pragma unroll
        for (int ky = 0; ky < 3; ++ky) {
            int gy = y + ky - 1;
            if ((unsigned)gy >= 16u) continue;
#pragma unroll
            for (int kx = 0; kx < 3; ++kx) {
                int gx = x + kx - 1;
                if ((unsigned)gx >= 16u) continue;
                acc = fma((double)w[ci * 9 + ky * 3 + kx],
                          (double)sE[ci * 256 + gy * 16 + gx], acc);
            }
        }
    }
    float v = (float)(acc + (double)bias[0]);
    xout[b * 256 + tid] = fmaxf(v, 0.f);
}

// ---- fused LSTM + gamma (blocks 0..63) and rowsum partials (64..87) ----
__global__ __launch_bounds__(256) void lstm_gamma_rowsum_kernel(
    const float* __restrict__ x, const float* __restrict__ wx,
    const float* __restrict__ bl, const float* __restrict__ w_param,
    const float* __restrict__ b_param, const float* __restrict__ w_out,
    float* __restrict__ h, double* __restrict__ rv, double* __restrict__ rsP)
{
    int blk = blockIdx.x;
    int tid = threadIdx.x;
    if (blk >= 64) {                                   // rowsum partial
        int idx = blk - 64;                            // 0..23
        int r = idx >> 3, c = idx & 7;                 // d-chunk c: 32 rows
        int m = tid;
        const float* wp = w_out + (size_t)(256 + r * 256 + c * 32) * 256 + m;
        double s[4] = {0, 0, 0, 0};
        for (int d0 = 0; d0 < 32; d0 += 4) {
#pragma unroll
            for (int k = 0; k < 4; ++k)
                s[k] += (double)wp[(size_t)(d0 + k) * 256];
        }
        rsP[(idx << 8) + m] = (s[0] + s[1]) + (s[2] + s[3]);
        return;
    }
    int b = blk, j = tid;
    __shared__ float sx[256];
    __shared__ float sh[256];
    __shared__ double sp[3][256];
    sx[j] = x[b * 256 + j];
    __syncthreads();
    // 8-way unrolled, independent accumulator streams (24 loads in flight)
    double zi[8], zg[8], zo[8];
#pragma unroll
    for (int k = 0; k < 8; ++k) { zi[k] = 0; zg[k] = 0; zo[k] = 0; }
    for (int d0 = 0; d0 < 256; d0 += 8) {
#pragma unroll
        for (int k = 0; k < 8; ++k) {
            double xv = (double)sx[d0 + k];
            const float* row = wx + (size_t)(d0 + k) * 1024;
            zi[k] = fma(xv, (double)row[j], zi[k]);
            zg[k] = fma(xv, (double)row[512 + j], zg[k]);
            zo[k] = fma(xv, (double)row[768 + j], zo[k]);
        }
    }
    double ziT = ((zi[0] + zi[1]) + (zi[2] + zi[3])) + ((zi[4] + zi[5]) + (zi[6] + zi[7]));
    double zgT = ((zg[0] + zg[1]) + (zg[2] + zg[3])) + ((zg[4] + zg[5]) + (zg[6] + zg[7]));
    double zoT = ((zo[0] + zo[1]) + (zo[2] + zo[3])) + ((zo[4] + zo[5]) + (zo[6] + zo[7]));
    float zif = (float)(ziT + (double)bl[j]);
    float zgf = (float)(zgT + (double)bl[512 + j]);
    float zof = (float)(zoT + (double)bl[768 + j]);
    double c = (1.0 / (1.0 + exp(-(double)zif))) * tanh((double)zgf);
    float cf = (float)c;
    double hh = (1.0 / (1.0 + exp(-(double)zof))) * tanh((double)cf);
    float hv = (float)hh;
    sh[j] = hv;
    h[b * 256 + j] = hv;
    __syncthreads();
#pragma unroll
    for (int r = 0; r < 3; ++r)
        sp[r][j] = (double)sh[j] * (double)w_param[(size_t)j * 3108 + r * 262 + 261];
    __syncthreads();
    if (j < 3) {
        double s = 0;
        for (int d = 0; d < 256; ++d) s += sp[j][d];
        float pf = (float)(s + (double)b_param[j * 262 + 261]);
        pf = fminf(fmaxf(pf, -20.f), 20.f);
        double gamma = log1p(exp((double)pf)) + 1.0;
        double q = pow(0.015625 + 1e-16, gamma);
        double wv = q / (64.0 * q + 1e-8);
        rv[b * 3 + j] = wv * 64.0 * 1e-6;
    }
}

// ---- fused ntm-out + conv2 -> A3 NHWC hi/lo (block b = one image) ----
__global__ __launch_bounds__(256) void ntmout_conv2_kernel(
    const float* __restrict__ h, const float* __restrict__ w_out,
    const float* __restrict__ b_out, const double* __restrict__ rv,
    const double* __restrict__ rsP, const float* __restrict__ w2,
    const float* __restrict__ b2,
    unsigned short* __restrict__ ohi, unsigned short* __restrict__ olo)
{
    int b = blockIdx.x, m = threadIdx.x;
    __shared__ float sh[256];
    __shared__ double srv[3];
    __shared__ float sNtm[256];
    sh[m] = h[b * 256 + m];
    if (m < 3) srv[m] = rv[b * 3 + m];
    __syncthreads();
    // 8-way unrolled h @ w_out dot (8 loads in flight)
    double a8[8];
#pragma unroll
    for (int k = 0; k < 8; ++k) a8[k] = 0;
    const float* wp = w_out + m;
    for (int d0 = 0; d0 < 256; d0 += 8) {
#pragma unroll
        for (int k = 0; k < 8; ++k)
            a8[k] = fma((double)sh[d0 + k], (double)wp[(size_t)(d0 + k) * 256], a8[k]);
    }
    double acc = ((a8[0] + a8[1]) + (a8[2] + a8[3])) + ((a8[4] + a8[5]) + (a8[6] + a8[7]));
    acc += (double)b_out[m];
#pragma unroll
    for (int r = 0; r < 3; ++r) {
        double rsum = 0;
#pragma unroll
        for (int c = 0; c < 8; ++c) rsum += rsP[((r * 8 + c) << 8) + m];
        acc += srv[r] * rsum;
    }
    acc = fmin(fmax(acc, -20.0), 20.0);
    sNtm[m] = (float)acc;                              // ntm[b] = 16x16 image
    __syncthreads();
    // conv2: 1->64 3x3 SAME + relu, output (y,x,co) with co innermost
    for (int p = m; p < 16384; p += 256) {
        int co = p & 63, x4 = (p >> 6) & 15, y4 = p >> 10;
        float a = b2[co];
#pragma unroll
        for (int ky = 0; ky < 3; ++ky) {
            int gy = y4 + ky - 1;
            if ((unsigned)gy >= 16u) continue;
#pragma unroll
            for (int kx = 0; kx < 3; ++kx) {
                int gx = x4 + kx - 1;
                if ((unsigned)gx >= 16u) continue;
                a = fmaf(w2[co * 9 + ky * 3 + kx], sNtm[gy * 16 + gx], a);
            }
        }
        unsigned short hh, ll;
        bf16split(fmaxf(a, 0.f), hh, ll);
        size_t adst = ((size_t)(b * 18 + y4 + 1) * 18 + x4 + 1) * 64 + co;
        ohi[adst] = hh; olo[adst] = ll;
    }
}

extern "C" void kernel_launch(void* const* d_in, const int* in_sizes, int n_in,
                              void* d_out, int out_size, void* d_ws, size_t ws_size,
                              hipStream_t stream)
{
    const float* inputs   = (const float*)d_in[0];
    const float* w_conv0  = (const float*)d_in[1];
    const float* b_conv0  = (const float*)d_in[2];
    const float* w_conv1  = (const float*)d_in[3];
    const float* b_conv1  = (const float*)d_in[4];
    const float* w_enc    = (const float*)d_in[5];
    const float* b_enc    = (const float*)d_in[6];
    const float* w_conv2  = (const float*)d_in[7];
    const float* b_conv2  = (const float*)d_in[8];
    const float* w_conv3  = (const float*)d_in[9];
    const float* b_conv3  = (const float*)d_in[10];
    const float* w_conv4  = (const float*)d_in[11];
    const float* b_conv4  = (const float*)d_in[12];
    const float* w_lstm_x = (const float*)d_in[13];
    // d_in[14] = w_lstm_h : dead (h0 == 0)
    const float* b_lstm   = (const float*)d_in[15];
    const float* w_param  = (const float*)d_in[16];
    const float* b_param  = (const float*)d_in[17];
    const float* w_out_   = (const float*)d_in[18];
    const float* b_out_   = (const float*)d_in[19];

    char* ws = (char*)d_ws;
    unsigned short* a1h = (unsigned short*)(ws + OFF_A1H);
    unsigned short* a1l = (unsigned short*)(ws + OFF_A1L);
    float*  t1  = (float*)(ws + OFF_T1);
    unsigned short* a3h = (unsigned short*)(ws + OFF_A3H);
    unsigned short* a3l = (unsigned short*)(ws + OFF_A3L);
    unsigned short* a4h = a1h;                         // A4 reuses A1
    unsigned short* a4l = a1l;
    unsigned short* whi1 = (unsigned short*)(ws + OFF_W1); unsigned short* wlo1 = whi1 + 36864;
    unsigned short* whi3 = (unsigned short*)(ws + OFF_W3); unsigned short* wlo3 = whi3 + 36864;
    unsigned short* whi4 = (unsigned short*)(ws + OFF_W4); unsigned short* wlo4 = whi4 + 36864;
    float*  xE  = (float*)(ws + OFF_XE);
    float*  h   = (float*)(ws + OFF_H);
    double* rv  = (double*)(ws + OFF_RV);
    double* rsP = (double*)(ws + OFF_RS);

    wprep_all_kernel<<<432, 256, 0, stream>>>(w_conv1, w_conv3, w_conv4,
                                              whi1, wlo1, whi3, wlo3, whi4, wlo4);
    halo_all_kernel<<<3200, 256, 0, stream>>>(a1h, a1l, a3h, a3l);

    conv0_pool_kernel<<<16384, 256, 0, stream>>>(inputs, w_conv0, b_conv0, a1h, a1l);
    conv1_mfma_kernel<<<512, 256, 0, stream>>>(a1h, a1l, whi1, wlo1, b_conv1, t1);
    pool_enc_kernel<<<64, 256, 0, stream>>>(t1, w_enc, b_enc, xE);

    lstm_gamma_rowsum_kernel<<<88, 256, 0, stream>>>(
        xE, w_lstm_x, b_lstm, w_param, b_param, w_out_, h, rv, rsP);
    ntmout_conv2_kernel<<<64, 256, 0, stream>>>(
        h, w_out_, b_out_, rv, rsP, w_conv2, b_conv2, a3h, a3l);

    conv3_mfma_kernel<<<512, 256, 0, stream>>>(a3h, a3l, whi3, wlo3, b_conv3, a4h, a4l);
    conv4_mfma_kernel<<<1024, 256, 0, stream>>>(a4h, a4l, whi4, wlo4, b_conv4, (float*)d_out);
}

// Round 11
// 277.666 us; speedup vs baseline: 1.1089x; 1.1089x over previous
//
#include <hip/hip_runtime.h>
#include <hip/hip_bf16.h>

// ============================================================================
// Round 11: NTM chain fp64 -> fp32 dots (fp64 kept only for transcendentals /
// scalar tails). R10 falsified the fp64-ILP fix: 24 f64 accumulators > VGPR
// budget -> compiler re-serialized (lstm 90us, ntmout 68us, ~850 cyc/iter).
// fp32 8-acc chains fit in 8 VGPRs. lstm restructured to 768-thr blocks
// (thread = gate-column), gamma via LDS tree reduce. pool_enc dot fp32 4-acc.
// Error budget: fp32 adds <=1e-6 abs vs 3.81e-6 floor / 2.41e-5 threshold.
// Convs / staging / layout identical to r10.
// ============================================================================

typedef __attribute__((ext_vector_type(8))) short short8;
typedef __attribute__((ext_vector_type(4))) float f32x4;

// ---- workspace layout (bytes) ----
static const size_t OFF_A1H = 0;                       // A1/A4 NHWC hi (B,34,34,64)
static const size_t OFF_A1L = 9469952;                 // -> end 18,939,904
static const size_t OFF_T1  = 18939904;                // t1 conv1 out NCHW f32 16MB
static const size_t OFF_A3H = 39911424;                // conv3 input NHWC (B,18,18,64)
static const size_t OFF_A3L = 42565632;                // -> end 45,219,840
static const size_t OFF_W1  = 45219840;                // packed whi+wlo 147,456 B/layer
static const size_t OFF_W3  = 45367296;
static const size_t OFF_W4  = 45514752;
static const size_t OFF_XE  = 45662208;                // xE (64,256) f32
static const size_t OFF_H   = 45727744;                // h  (64,256) f32
static const size_t OFF_RV  = 45793280;                // rv (64,3) f64
static const size_t OFF_RS  = 45794816;                // rs_part (24,256) f64 49,152B

__device__ inline void bf16split(float v, unsigned short& h, unsigned short& l) {
    __hip_bfloat16 hb = __float2bfloat16(v);
    float hf = __bfloat162float(hb);
    __hip_bfloat16 lb = __float2bfloat16(v - hf);
    h = __builtin_bit_cast(unsigned short, hb);
    l = __builtin_bit_cast(unsigned short, lb);
}

// ---- weight prep, all 3 layers: (co,ci,3,3) f32 -> fragment-packed hi/lo ----
__global__ void wprep_all_kernel(
    const float* __restrict__ w1, const float* __restrict__ w3,
    const float* __restrict__ w4,
    unsigned short* __restrict__ whi1, unsigned short* __restrict__ wlo1,
    unsigned short* __restrict__ whi3, unsigned short* __restrict__ wlo3,
    unsigned short* __restrict__ whi4, unsigned short* __restrict__ wlo4)
{
    int layer = blockIdx.x / 144;
    int r = (blockIdx.x % 144) * 256 + threadIdx.x;    // < 36864
    const float* w = layer == 0 ? w1 : (layer == 1 ? w3 : w4);
    unsigned short* hi = layer == 0 ? whi1 : (layer == 1 ? whi3 : whi4);
    unsigned short* lo = layer == 0 ? wlo1 : (layer == 1 ? wlo3 : wlo4);
    int j  = r & 7;
    int ln = (r >> 3) & 63;
    int n  = (r >> 9) & 3;
    int ch = (r >> 11) & 1;
    int t  = r >> 12;
    int lc = ln & 15, kg = ln >> 4;
    int co = n * 16 + lc;
    int ci = ch * 32 + kg * 8 + j;
    unsigned short h, l;
    bf16split(w[(co * 64 + ci) * 9 + t], h, l);
    hi[r] = h; lo[r] = l;
}

// ---- zero halo rings of a1 (S=32) and a3 (S=16) in one kernel ----
__device__ inline void halo_zero_one(unsigned short* hi, unsigned short* lo,
                                     int S, int idx)
{
    int P = S + 2, ring = 4 * S + 4;
    int co = idx & 63;
    int cell = (idx >> 6) % ring;
    int b = (idx >> 6) / ring;
    int y, x;
    if (cell < P)            { y = 0;     x = cell; }
    else if (cell < 2 * P)   { y = P - 1; x = cell - P; }
    else { int c2 = cell - 2 * P; y = 1 + (c2 >> 1); x = (c2 & 1) ? P - 1 : 0; }
    size_t a = ((size_t)(b * P + y) * P + x) * 64 + co;
    hi[a] = 0; lo[a] = 0;
}

__global__ void halo_all_kernel(unsigned short* __restrict__ a1h,
                                unsigned short* __restrict__ a1l,
                                unsigned short* __restrict__ a3h,
                                unsigned short* __restrict__ a3l)
{
    int idx = blockIdx.x * 256 + threadIdx.x;          // 819,200 total
    if (idx < 540672) halo_zero_one(a1h, a1l, 32, idx);
    else              halo_zero_one(a3h, a3l, 16, idx - 540672);
}

// ---- fused conv0 (1->64, 3x3 SAME, relu) + avgpool2 -> A1 NHWC hi/lo ----
__global__ __launch_bounds__(256) void conv0_pool_kernel(
    const float* __restrict__ in, const float* __restrict__ w,
    const float* __restrict__ bias,
    unsigned short* __restrict__ ohi, unsigned short* __restrict__ olo)
{
    int idx = blockIdx.x * 256 + threadIdx.x;          // 4,194,304
    int co = idx & 63, x = (idx >> 6) & 31, y = (idx >> 11) & 31, b = idx >> 16;
    float w9[9];
#pragma unroll
    for (int t = 0; t < 9; ++t) w9[t] = w[co * 9 + t];
    float bv = bias[co];
    const float* ip = in + (size_t)b * 4096;
    float p[4][4];
#pragma unroll
    for (int r = 0; r < 4; ++r) {
        int gy = 2 * y - 1 + r;
#pragma unroll
        for (int c = 0; c < 4; ++c) {
            int gx = 2 * x - 1 + c;
            float v = 0.f;
            if ((unsigned)gy < 64u && (unsigned)gx < 64u) v = ip[gy * 64 + gx];
            p[r][c] = v;
        }
    }
    float s4 = 0.f;
#pragma unroll
    for (int dy = 0; dy < 2; ++dy)
#pragma unroll
        for (int dx = 0; dx < 2; ++dx) {
            float a = bv;
#pragma unroll
            for (int ky = 0; ky < 3; ++ky)
#pragma unroll
                for (int kx = 0; kx < 3; ++kx)
                    a = fmaf(w9[ky * 3 + kx], p[dy + ky][dx + kx], a);
            s4 += fmaxf(a, 0.f);
        }
    unsigned short h, l;
    bf16split(s4 * 0.25f, h, l);
    size_t a = ((size_t)(b * 34 + y + 1) * 34 + x + 1) * 64 + co;
    ohi[a] = h; olo[a] = l;
}

// ---- MFMA implicit-GEMM conv body: 256 thr / 4 waves, ROWS rows per wave ----
template <int UP, int H, int ROWS, bool NHWC_OUT>
__device__ __forceinline__ void conv_mfma_body(
    const unsigned short* __restrict__ ahi, const unsigned short* __restrict__ alo,
    const unsigned short* __restrict__ whiP, const unsigned short* __restrict__ wloP,
    const float* __restrict__ bias,
    float* __restrict__ outf, unsigned short* __restrict__ ohi,
    unsigned short* __restrict__ olo)
{
    constexpr int TILEH = 4 * ROWS;
    constexpr int SRC   = H >> UP;
    constexpr int PITCH = SRC + 2;
    constexpr int TPR   = H / 16;
    constexpr int TPC   = H / TILEH;
    constexpr int AH    = (UP ? TILEH / 2 : TILEH) + 2;
    constexpr int AW    = UP ? 10 : 18;
    constexpr int NPX   = AH * AW;

    int b  = blockIdx.x / (TPC * TPR);
    int tt = blockIdx.x % (TPC * TPR);
    int y0 = (tt / TPR) * TILEH, x0 = (tt % TPR) * 16;
    const int tid = threadIdx.x;
    const int wv = tid >> 6, lane = tid & 63;
    const int lc = lane & 15, kg = lane >> 4;

    __shared__ unsigned short sAhi[NPX * 64];
    __shared__ unsigned short sAlo[NPX * 64];
    __shared__ unsigned short sW[2][4096];             // [buf][hi 2048 | lo 2048]

    const int r0 = ((y0 - 1) >> UP) + 1;
    const int c0 = ((x0 - 1) >> UP) + 1;

    for (int c = tid; c < NPX * 8; c += 256) {
        int pix = c >> 3, sub = c & 7;
        int py = pix / AW, px = pix - py * AW;
        size_t g = ((size_t)(b * PITCH + r0 + py) * PITCH + (c0 + px)) * 64 + sub * 8;
        int l = (pix * 64 + sub * 8) ^ ((pix & 7) << 3);
        *(short8*)&sAhi[l] = *(const short8*)&ahi[g];
        *(short8*)&sAlo[l] = *(const short8*)&alo[g];
    }
    for (int c = tid; c < 512; c += 256) {
        if (c < 256) *(short8*)&sW[0][c * 8] = *(const short8*)&whiP[c * 8];
        else *(short8*)&sW[0][2048 + (c - 256) * 8] = *(const short8*)&wloP[(c - 256) * 8];
    }
    __syncthreads();

    int lxv[3], lyv[ROWS + 2];
#pragma unroll
    for (int kx = 0; kx < 3; ++kx)
        lxv[kx] = (((x0 + lc + kx - 1) >> UP) + 1) - c0;
#pragma unroll
    for (int r = 0; r < ROWS + 2; ++r)
        lyv[r] = (((y0 + ROWS * wv + r - 1) >> UP) + 1) - r0;

    f32x4 acc[ROWS][4];
#pragma unroll
    for (int m = 0; m < ROWS; ++m)
#pragma unroll
        for (int n = 0; n < 4; ++n) acc[m][n] = f32x4{0.f, 0.f, 0.f, 0.f};

#pragma unroll
    for (int k = 0; k < 18; ++k) {                     // k = t*2 + ch
        if (k + 1 < 18) {                              // prefetch next W slice
            int slb = (k + 1) * 2048;
            for (int c = tid; c < 512; c += 256) {
                if (c < 256) *(short8*)&sW[(k + 1) & 1][c * 8] =
                    *(const short8*)&whiP[slb + c * 8];
                else *(short8*)&sW[(k + 1) & 1][2048 + (c - 256) * 8] =
                    *(const short8*)&wloP[slb + (c - 256) * 8];
            }
        }
        const int t = k >> 1, ch = k & 1;
        const int ky = t / 3, kx = t - ky * 3;
        short8 ah[ROWS], al[ROWS];
#pragma unroll
        for (int m = 0; m < ROWS; ++m) {
            int p = lyv[ky + m] * AW + lxv[kx];
            int i = (p * 64 + ch * 32 + kg * 8) ^ ((p & 7) << 3);
            ah[m] = *(const short8*)&sAhi[i];
            al[m] = *(const short8*)&sAlo[i];
        }
        const unsigned short* wb = &sW[k & 1][0];
#pragma unroll
        for (int n = 0; n < 4; ++n) {
            short8 bh = *(const short8*)&wb[(n * 64 + lane) * 8];
            short8 bl = *(const short8*)&wb[2048 + (n * 64 + lane) * 8];
#pragma unroll
            for (int m = 0; m < ROWS; ++m) {
                acc[m][n] = __builtin_amdgcn_mfma_f32_16x16x32_bf16(ah[m], bh, acc[m][n], 0, 0, 0);
                acc[m][n] = __builtin_amdgcn_mfma_f32_16x16x32_bf16(ah[m], bl, acc[m][n], 0, 0, 0);
                acc[m][n] = __builtin_amdgcn_mfma_f32_16x16x32_bf16(al[m], bh, acc[m][n], 0, 0, 0);
            }
        }
        __syncthreads();
    }

    if (NHWC_OUT) {
        const int opitch = H + 2;
#pragma unroll
        for (int n = 0; n < 4; ++n) {
            int co = n * 16 + lc;
            float bv = bias[co];
#pragma unroll
            for (int m = 0; m < ROWS; ++m) {
                int row = y0 + ROWS * wv + m, cb = x0 + kg * 4;
                f32x4 v = acc[m][n];
#pragma unroll
                for (int j = 0; j < 4; ++j) {
                    float val = fmaxf(v[j] + bv, 0.f);
                    unsigned short h, l;
                    bf16split(val, h, l);
                    size_t a = ((size_t)(b * opitch + row + 1) * opitch + cb + j + 1) * 64 + co;
                    ohi[a] = h; olo[a] = l;
                }
            }
        }
    } else {
#pragma unroll
        for (int n = 0; n < 4; ++n) {
            int co = n * 16 + lc;
            float bv = bias[co];
#pragma unroll
            for (int m = 0; m < ROWS; ++m) {
                int row = y0 + ROWS * wv + m, cb = x0 + kg * 4;
                f32x4 v = acc[m][n], res;
                res.x = fmaxf(v.x + bv, 0.f);
                res.y = fmaxf(v.y + bv, 0.f);
                res.z = fmaxf(v.z + bv, 0.f);
                res.w = fmaxf(v.w + bv, 0.f);
                *(f32x4*)&outf[((size_t)(b * 64 + co) * H + row) * H + cb] = res;
            }
        }
    }
}

__global__ __launch_bounds__(256, 2) void conv1_mfma_kernel(
    const unsigned short* __restrict__ ahi, const unsigned short* __restrict__ alo,
    const unsigned short* __restrict__ whiP, const unsigned short* __restrict__ wloP,
    const float* __restrict__ bias, float* __restrict__ outf)
{ conv_mfma_body<0, 32, 2, false>(ahi, alo, whiP, wloP, bias, outf, nullptr, nullptr); }

__global__ __launch_bounds__(256, 3) void conv3_mfma_kernel(
    const unsigned short* __restrict__ ahi, const unsigned short* __restrict__ alo,
    const unsigned short* __restrict__ whiP, const unsigned short* __restrict__ wloP,
    const float* __restrict__ bias,
    unsigned short* __restrict__ ohi, unsigned short* __restrict__ olo)
{ conv_mfma_body<1, 32, 2, true>(ahi, alo, whiP, wloP, bias, nullptr, ohi, olo); }

__global__ __launch_bounds__(256, 3) void conv4_mfma_kernel(
    const unsigned short* __restrict__ ahi, const unsigned short* __restrict__ alo,
    const unsigned short* __restrict__ whiP, const unsigned short* __restrict__ wloP,
    const float* __restrict__ bias, float* __restrict__ outf)
{ conv_mfma_body<1, 64, 4, false>(ahi, alo, whiP, wloP, bias, outf, nullptr, nullptr); }

// ---- fused avgpool2 + enc conv: t1 (64,64,32,32) -> xE (64,256), fp32 ----
__global__ __launch_bounds__(256) void pool_enc_kernel(
    const float* __restrict__ t1, const float* __restrict__ w,
    const float* __restrict__ bias, float* __restrict__ xout)
{
    int b = blockIdx.x; int tid = threadIdx.x;
    __shared__ float sE[16384];                        // pooled (64,16,16)
#pragma unroll 4
    for (int p = tid; p < 16384; p += 256) {
        int ch = p >> 8, y = (p >> 4) & 15, x = p & 15;
        const float* ip = t1 + ((size_t)(b * 64 + ch) * 32 + 2 * y) * 32 + 2 * x;
        sE[p] = (ip[0] + ip[1] + ip[32] + ip[33]) * 0.25f;
    }
    __syncthreads();
    int y = tid >> 4, x = tid & 15;
    float acc[4] = {0.f, 0.f, 0.f, 0.f};
    for (int ci = 0; ci < 64; ++ci) {
#pragma unroll
        for (int ky = 0; ky < 3; ++ky) {
            int gy = y + ky - 1;
            if ((unsigned)gy >= 16u) continue;
#pragma unroll
            for (int kx = 0; kx < 3; ++kx) {
                int gx = x + kx - 1;
                if ((unsigned)gx >= 16u) continue;
                acc[ci & 3] = fmaf(w[ci * 9 + ky * 3 + kx],
                                   sE[ci * 256 + gy * 16 + gx], acc[ci & 3]);
            }
        }
    }
    float v = ((acc[0] + acc[1]) + (acc[2] + acc[3])) + bias[0];
    xout[b * 256 + tid] = fmaxf(v, 0.f);
}

// ---- fused LSTM + gamma (blocks 0..63, 768 thr) and rowsum (64..87) ----
__global__ __launch_bounds__(768) void lstm_gamma_rowsum_kernel(
    const float* __restrict__ x, const float* __restrict__ wx,
    const float* __restrict__ bl, const float* __restrict__ w_param,
    const float* __restrict__ b_param, const float* __restrict__ w_out,
    float* __restrict__ h, double* __restrict__ rv, double* __restrict__ rsP)
{
    int blk = blockIdx.x;
    int t = threadIdx.x;
    if (blk >= 64) {                                   // rowsum partial blocks
        if (t >= 256) return;
        int idx = blk - 64;                            // 0..23
        int r = idx >> 3, c = idx & 7;                 // d-chunk c: 32 rows
        const float* wp = w_out + (size_t)(256 + r * 256 + c * 32) * 256 + t;
        double s[4] = {0, 0, 0, 0};
        for (int d0 = 0; d0 < 32; d0 += 4) {
#pragma unroll
            for (int k = 0; k < 4; ++k)
                s[k] += (double)wp[(size_t)(d0 + k) * 256];
        }
        rsP[(idx << 8) + t] = (s[0] + s[1]) + (s[2] + s[3]);
        return;
    }
    int b = blk;
    __shared__ float sx[256];
    __shared__ float zb[3][256];
    __shared__ float sh[256];
    __shared__ double red[3][256];
    if (t < 256) sx[t] = x[b * 256 + t];
    __syncthreads();
    {   // z-GEMM: thread = (gate g, column j), fp32 8-acc dot
        int g = t >> 8, j = t & 255;
        int off = (g == 0) ? 0 : (g == 1 ? 512 : 768);
        const float* wp = wx + off + j;
        float acc[8];
#pragma unroll
        for (int k = 0; k < 8; ++k) acc[k] = 0.f;
        for (int d0 = 0; d0 < 256; d0 += 8) {
            float xv[8], wv[8];
#pragma unroll
            for (int k = 0; k < 8; ++k) xv[k] = sx[d0 + k];
#pragma unroll
            for (int k = 0; k < 8; ++k) wv[k] = wp[(size_t)(d0 + k) * 1024];
#pragma unroll
            for (int k = 0; k < 8; ++k) acc[k] = fmaf(xv[k], wv[k], acc[k]);
        }
        zb[g][j] = ((acc[0] + acc[1]) + (acc[2] + acc[3]))
                 + ((acc[4] + acc[5]) + (acc[6] + acc[7]));
    }
    __syncthreads();
    if (t < 256) {                                     // gates + h
        int j = t;
        float zif = (float)((double)zb[0][j] + (double)bl[j]);
        float zgf = (float)((double)zb[1][j] + (double)bl[512 + j]);
        float zof = (float)((double)zb[2][j] + (double)bl[768 + j]);
        double c = (1.0 / (1.0 + exp(-(double)zif))) * tanh((double)zgf);
        float cf = (float)c;
        double hh = (1.0 / (1.0 + exp(-(double)zof))) * tanh((double)cf);
        float hv = (float)hh;
        sh[j] = hv;
        h[b * 256 + j] = hv;
    }
    __syncthreads();
    {   // gamma: products then LDS tree reduce (3 heads x 256)
        int r = t >> 8, j = t & 255;
        red[r][j] = (double)sh[j] * (double)w_param[(size_t)j * 3108 + r * 262 + 261];
        __syncthreads();
#pragma unroll
        for (int s = 128; s > 0; s >>= 1) {
            if (j < s) red[r][j] += red[r][j + s];
            __syncthreads();
        }
        if (j == 0) {
            double s = red[r][0];
            float pf = (float)(s + (double)b_param[r * 262 + 261]);
            pf = fminf(fmaxf(pf, -20.f), 20.f);
            double gamma = log1p(exp((double)pf)) + 1.0;
            double q = pow(0.015625 + 1e-16, gamma);
            double wv = q / (64.0 * q + 1e-8);
            rv[b * 3 + r] = wv * 64.0 * 1e-6;
        }
    }
}

// ---- fused ntm-out + conv2 -> A3 NHWC hi/lo (block b = one image) ----
__global__ __launch_bounds__(256) void ntmout_conv2_kernel(
    const float* __restrict__ h, const float* __restrict__ w_out,
    const float* __restrict__ b_out, const double* __restrict__ rv,
    const double* __restrict__ rsP, const float* __restrict__ w2,
    const float* __restrict__ b2,
    unsigned short* __restrict__ ohi, unsigned short* __restrict__ olo)
{
    int b = blockIdx.x, m = threadIdx.x;
    __shared__ float sh[256];
    __shared__ double srv[3];
    __shared__ float sNtm[256];
    sh[m] = h[b * 256 + m];
    if (m < 3) srv[m] = rv[b * 3 + m];
    __syncthreads();
    // fp32 8-acc dot (8 loads in flight, 8 VGPR accumulators)
    float a8[8];
#pragma unroll
    for (int k = 0; k < 8; ++k) a8[k] = 0.f;
    const float* wp = w_out + m;
    for (int d0 = 0; d0 < 256; d0 += 8) {
        float hv8[8], wv8[8];
#pragma unroll
        for (int k = 0; k < 8; ++k) hv8[k] = sh[d0 + k];
#pragma unroll
        for (int k = 0; k < 8; ++k) wv8[k] = wp[(size_t)(d0 + k) * 256];
#pragma unroll
        for (int k = 0; k < 8; ++k) a8[k] = fmaf(hv8[k], wv8[k], a8[k]);
    }
    float dotf = ((a8[0] + a8[1]) + (a8[2] + a8[3])) + ((a8[4] + a8[5]) + (a8[6] + a8[7]));
    double acc = (double)dotf + (double)b_out[m];
#pragma unroll
    for (int r = 0; r < 3; ++r) {
        double rsum = 0;
#pragma unroll
        for (int c = 0; c < 8; ++c) rsum += rsP[((r * 8 + c) << 8) + m];
        acc += srv[r] * rsum;
    }
    acc = fmin(fmax(acc, -20.0), 20.0);
    sNtm[m] = (float)acc;                              // ntm[b] = 16x16 image
    __syncthreads();
    // conv2: 1->64 3x3 SAME + relu, output (y,x,co) with co innermost
    for (int p = m; p < 16384; p += 256) {
        int co = p & 63, x4 = (p >> 6) & 15, y4 = p >> 10;
        float a = b2[co];
#pragma unroll
        for (int ky = 0; ky < 3; ++ky) {
            int gy = y4 + ky - 1;
            if ((unsigned)gy >= 16u) continue;
#pragma unroll
            for (int kx = 0; kx < 3; ++kx) {
                int gx = x4 + kx - 1;
                if ((unsigned)gx >= 16u) continue;
                a = fmaf(w2[co * 9 + ky * 3 + kx], sNtm[gy * 16 + gx], a);
            }
        }
        unsigned short hh, ll;
        bf16split(fmaxf(a, 0.f), hh, ll);
        size_t adst = ((size_t)(b * 18 + y4 + 1) * 18 + x4 + 1) * 64 + co;
        ohi[adst] = hh; olo[adst] = ll;
    }
}

extern "C" void kernel_launch(void* const* d_in, const int* in_sizes, int n_in,
                              void* d_out, int out_size, void* d_ws, size_t ws_size,
                              hipStream_t stream)
{
    const float* inputs   = (const float*)d_in[0];
    const float* w_conv0  = (const float*)d_in[1];
    const float* b_conv0  = (const float*)d_in[2];
    const float* w_conv1  = (const float*)d_in[3];
    const float* b_conv1  = (const float*)d_in[4];
    const float* w_enc    = (const float*)d_in[5];
    const float* b_enc    = (const float*)d_in[6];
    const float* w_conv2  = (const float*)d_in[7];
    const float* b_conv2  = (const float*)d_in[8];
    const float* w_conv3  = (const float*)d_in[9];
    const float* b_conv3  = (const float*)d_in[10];
    const float* w_conv4  = (const float*)d_in[11];
    const float* b_conv4  = (const float*)d_in[12];
    const float* w_lstm_x = (const float*)d_in[13];
    // d_in[14] = w_lstm_h : dead (h0 == 0)
    const float* b_lstm   = (const float*)d_in[15];
    const float* w_param  = (const float*)d_in[16];
    const float* b_param  = (const float*)d_in[17];
    const float* w_out_   = (const float*)d_in[18];
    const float* b_out_   = (const float*)d_in[19];

    char* ws = (char*)d_ws;
    unsigned short* a1h = (unsigned short*)(ws + OFF_A1H);
    unsigned short* a1l = (unsigned short*)(ws + OFF_A1L);
    float*  t1  = (float*)(ws + OFF_T1);
    unsigned short* a3h = (unsigned short*)(ws + OFF_A3H);
    unsigned short* a3l = (unsigned short*)(ws + OFF_A3L);
    unsigned short* a4h = a1h;                         // A4 reuses A1
    unsigned short* a4l = a1l;
    unsigned short* whi1 = (unsigned short*)(ws + OFF_W1); unsigned short* wlo1 = whi1 + 36864;
    unsigned short* whi3 = (unsigned short*)(ws + OFF_W3); unsigned short* wlo3 = whi3 + 36864;
    unsigned short* whi4 = (unsigned short*)(ws + OFF_W4); unsigned short* wlo4 = whi4 + 36864;
    float*  xE  = (float*)(ws + OFF_XE);
    float*  h   = (float*)(ws + OFF_H);
    double* rv  = (double*)(ws + OFF_RV);
    double* rsP = (double*)(ws + OFF_RS);

    wprep_all_kernel<<<432, 256, 0, stream>>>(w_conv1, w_conv3, w_conv4,
                                              whi1, wlo1, whi3, wlo3, whi4, wlo4);
    halo_all_kernel<<<3200, 256, 0, stream>>>(a1h, a1l, a3h, a3l);

    conv0_pool_kernel<<<16384, 256, 0, stream>>>(inputs, w_conv0, b_conv0, a1h, a1l);
    conv1_mfma_kernel<<<512, 256, 0, stream>>>(a1h, a1l, whi1, wlo1, b_conv1, t1);
    pool_enc_kernel<<<64, 256, 0, stream>>>(t1, w_enc, b_enc, xE);

    lstm_gamma_rowsum_kernel<<<88, 768, 0, stream>>>(
        xE, w_lstm_x, b_lstm, w_param, b_param, w_out_, h, rv, rsP);
    ntmout_conv2_kernel<<<64, 256, 0, stream>>>(
        h, w_out_, b_out_, rv, rsP, w_conv2, b_conv2, a3h, a3l);

    conv3_mfma_kernel<<<512, 256, 0, stream>>>(a3h, a3l, whi3, wlo3, b_conv3, a4h, a4l);
    conv4_mfma_kernel<<<1024, 256, 0, stream>>>(a4h, a4l, whi4, wlo4, b_conv4, (float*)d_out);
}

// Round 12
// 209.365 us; speedup vs baseline: 1.4707x; 1.3262x over previous
//
#include <hip/hip_runtime.h>
#include <hip/hip_bf16.h>

// ============================================================================
// Round 12: fuse the whole NTM chain (pool+enc+LSTM+gamma+ntmout+conv2) into
// ONE 64-block x 1024-thread kernel, all intermediates in LDS. R11 showed the
// chain kernels invariant at ~62us regardless of dot implementation: 1
// wave/SIMD on 64 CUs -> zero latency hiding + 3 kernel-boundary round trips.
// 16 waves/block = 4/SIMD TLP. rowsum (weights-only) moved into prep kernel.
// Phase math = r11's validated fp32 structures (reassociation-only deltas).
// Launches 9 -> 7. Convs byte-identical to r11.
// ============================================================================

typedef __attribute__((ext_vector_type(8))) short short8;
typedef __attribute__((ext_vector_type(4))) float f32x4;

// ---- workspace layout (bytes) ----
static const size_t OFF_A1H = 0;                       // A1/A4 NHWC hi (B,34,34,64)
static const size_t OFF_A1L = 9469952;                 // -> end 18,939,904
static const size_t OFF_T1  = 18939904;                // t1 conv1 out NCHW f32 16MB
static const size_t OFF_A3H = 39911424;                // conv3 input NHWC (B,18,18,64)
static const size_t OFF_A3L = 42565632;                // -> end 45,219,840
static const size_t OFF_W1  = 45219840;                // packed whi+wlo 147,456 B/layer
static const size_t OFF_W3  = 45367296;
static const size_t OFF_W4  = 45514752;
static const size_t OFF_RS  = 45662208;                // rs_part (24,256) f64 49,152B

__device__ inline void bf16split(float v, unsigned short& h, unsigned short& l) {
    __hip_bfloat16 hb = __float2bfloat16(v);
    float hf = __bfloat162float(hb);
    __hip_bfloat16 lb = __float2bfloat16(v - hf);
    h = __builtin_bit_cast(unsigned short, hb);
    l = __builtin_bit_cast(unsigned short, lb);
}

// ---- prep: weight fragment-pack (blocks 0..431) + rowsum partials (432..455)
__global__ void wprep_rowsum_kernel(
    const float* __restrict__ w1, const float* __restrict__ w3,
    const float* __restrict__ w4, const float* __restrict__ w_out,
    unsigned short* __restrict__ whi1, unsigned short* __restrict__ wlo1,
    unsigned short* __restrict__ whi3, unsigned short* __restrict__ wlo3,
    unsigned short* __restrict__ whi4, unsigned short* __restrict__ wlo4,
    double* __restrict__ rsP)
{
    int blk = blockIdx.x;
    if (blk >= 432) {                                  // rowsum partials (bit-identical to r11)
        int idx = blk - 432;                           // 0..23
        int r = idx >> 3, c = idx & 7;
        int m = threadIdx.x;
        const float* wp = w_out + (size_t)(256 + r * 256 + c * 32) * 256 + m;
        double s[4] = {0, 0, 0, 0};
        for (int d0 = 0; d0 < 32; d0 += 4) {
#pragma unroll
            for (int k = 0; k < 4; ++k)
                s[k] += (double)wp[(size_t)(d0 + k) * 256];
        }
        rsP[(idx << 8) + m] = (s[0] + s[1]) + (s[2] + s[3]);
        return;
    }
    int layer = blk / 144;
    int r = (blk % 144) * 256 + threadIdx.x;           // < 36864
    const float* w = layer == 0 ? w1 : (layer == 1 ? w3 : w4);
    unsigned short* hi = layer == 0 ? whi1 : (layer == 1 ? whi3 : whi4);
    unsigned short* lo = layer == 0 ? wlo1 : (layer == 1 ? wlo3 : wlo4);
    int j  = r & 7;
    int ln = (r >> 3) & 63;
    int n  = (r >> 9) & 3;
    int ch = (r >> 11) & 1;
    int t  = r >> 12;
    int lc = ln & 15, kg = ln >> 4;
    int co = n * 16 + lc;
    int ci = ch * 32 + kg * 8 + j;
    unsigned short h, l;
    bf16split(w[(co * 64 + ci) * 9 + t], h, l);
    hi[r] = h; lo[r] = l;
}

// ---- zero halo rings of a1 (S=32) and a3 (S=16) in one kernel ----
__device__ inline void halo_zero_one(unsigned short* hi, unsigned short* lo,
                                     int S, int idx)
{
    int P = S + 2, ring = 4 * S + 4;
    int co = idx & 63;
    int cell = (idx >> 6) % ring;
    int b = (idx >> 6) / ring;
    int y, x;
    if (cell < P)            { y = 0;     x = cell; }
    else if (cell < 2 * P)   { y = P - 1; x = cell - P; }
    else { int c2 = cell - 2 * P; y = 1 + (c2 >> 1); x = (c2 & 1) ? P - 1 : 0; }
    size_t a = ((size_t)(b * P + y) * P + x) * 64 + co;
    hi[a] = 0; lo[a] = 0;
}

__global__ void halo_all_kernel(unsigned short* __restrict__ a1h,
                                unsigned short* __restrict__ a1l,
                                unsigned short* __restrict__ a3h,
                                unsigned short* __restrict__ a3l)
{
    int idx = blockIdx.x * 256 + threadIdx.x;          // 819,200 total
    if (idx < 540672) halo_zero_one(a1h, a1l, 32, idx);
    else              halo_zero_one(a3h, a3l, 16, idx - 540672);
}

// ---- fused conv0 (1->64, 3x3 SAME, relu) + avgpool2 -> A1 NHWC hi/lo ----
__global__ __launch_bounds__(256) void conv0_pool_kernel(
    const float* __restrict__ in, const float* __restrict__ w,
    const float* __restrict__ bias,
    unsigned short* __restrict__ ohi, unsigned short* __restrict__ olo)
{
    int idx = blockIdx.x * 256 + threadIdx.x;          // 4,194,304
    int co = idx & 63, x = (idx >> 6) & 31, y = (idx >> 11) & 31, b = idx >> 16;
    float w9[9];
#pragma unroll
    for (int t = 0; t < 9; ++t) w9[t] = w[co * 9 + t];
    float bv = bias[co];
    const float* ip = in + (size_t)b * 4096;
    float p[4][4];
#pragma unroll
    for (int r = 0; r < 4; ++r) {
        int gy = 2 * y - 1 + r;
#pragma unroll
        for (int c = 0; c < 4; ++c) {
            int gx = 2 * x - 1 + c;
            float v = 0.f;
            if ((unsigned)gy < 64u && (unsigned)gx < 64u) v = ip[gy * 64 + gx];
            p[r][c] = v;
        }
    }
    float s4 = 0.f;
#pragma unroll
    for (int dy = 0; dy < 2; ++dy)
#pragma unroll
        for (int dx = 0; dx < 2; ++dx) {
            float a = bv;
#pragma unroll
            for (int ky = 0; ky < 3; ++ky)
#pragma unroll
                for (int kx = 0; kx < 3; ++kx)
                    a = fmaf(w9[ky * 3 + kx], p[dy + ky][dx + kx], a);
            s4 += fmaxf(a, 0.f);
        }
    unsigned short h, l;
    bf16split(s4 * 0.25f, h, l);
    size_t a = ((size_t)(b * 34 + y + 1) * 34 + x + 1) * 64 + co;
    ohi[a] = h; olo[a] = l;
}

// ---- MFMA implicit-GEMM conv body: 256 thr / 4 waves, ROWS rows per wave ----
template <int UP, int H, int ROWS, bool NHWC_OUT>
__device__ __forceinline__ void conv_mfma_body(
    const unsigned short* __restrict__ ahi, const unsigned short* __restrict__ alo,
    const unsigned short* __restrict__ whiP, const unsigned short* __restrict__ wloP,
    const float* __restrict__ bias,
    float* __restrict__ outf, unsigned short* __restrict__ ohi,
    unsigned short* __restrict__ olo)
{
    constexpr int TILEH = 4 * ROWS;
    constexpr int SRC   = H >> UP;
    constexpr int PITCH = SRC + 2;
    constexpr int TPR   = H / 16;
    constexpr int TPC   = H / TILEH;
    constexpr int AH    = (UP ? TILEH / 2 : TILEH) + 2;
    constexpr int AW    = UP ? 10 : 18;
    constexpr int NPX   = AH * AW;

    int b  = blockIdx.x / (TPC * TPR);
    int tt = blockIdx.x % (TPC * TPR);
    int y0 = (tt / TPR) * TILEH, x0 = (tt % TPR) * 16;
    const int tid = threadIdx.x;
    const int wv = tid >> 6, lane = tid & 63;
    const int lc = lane & 15, kg = lane >> 4;

    __shared__ unsigned short sAhi[NPX * 64];
    __shared__ unsigned short sAlo[NPX * 64];
    __shared__ unsigned short sW[2][4096];             // [buf][hi 2048 | lo 2048]

    const int r0 = ((y0 - 1) >> UP) + 1;
    const int c0 = ((x0 - 1) >> UP) + 1;

    for (int c = tid; c < NPX * 8; c += 256) {
        int pix = c >> 3, sub = c & 7;
        int py = pix / AW, px = pix - py * AW;
        size_t g = ((size_t)(b * PITCH + r0 + py) * PITCH + (c0 + px)) * 64 + sub * 8;
        int l = (pix * 64 + sub * 8) ^ ((pix & 7) << 3);
        *(short8*)&sAhi[l] = *(const short8*)&ahi[g];
        *(short8*)&sAlo[l] = *(const short8*)&alo[g];
    }
    for (int c = tid; c < 512; c += 256) {
        if (c < 256) *(short8*)&sW[0][c * 8] = *(const short8*)&whiP[c * 8];
        else *(short8*)&sW[0][2048 + (c - 256) * 8] = *(const short8*)&wloP[(c - 256) * 8];
    }
    __syncthreads();

    int lxv[3], lyv[ROWS + 2];
#pragma unroll
    for (int kx = 0; kx < 3; ++kx)
        lxv[kx] = (((x0 + lc + kx - 1) >> UP) + 1) - c0;
#pragma unroll
    for (int r = 0; r < ROWS + 2; ++r)
        lyv[r] = (((y0 + ROWS * wv + r - 1) >> UP) + 1) - r0;

    f32x4 acc[ROWS][4];
#pragma unroll
    for (int m = 0; m < ROWS; ++m)
#pragma unroll
        for (int n = 0; n < 4; ++n) acc[m][n] = f32x4{0.f, 0.f, 0.f, 0.f};

#pragma unroll
    for (int k = 0; k < 18; ++k) {                     // k = t*2 + ch
        if (k + 1 < 18) {                              // prefetch next W slice
            int slb = (k + 1) * 2048;
            for (int c = tid; c < 512; c += 256) {
                if (c < 256) *(short8*)&sW[(k + 1) & 1][c * 8] =
                    *(const short8*)&whiP[slb + c * 8];
                else *(short8*)&sW[(k + 1) & 1][2048 + (c - 256) * 8] =
                    *(const short8*)&wloP[slb + (c - 256) * 8];
            }
        }
        const int t = k >> 1, ch = k & 1;
        const int ky = t / 3, kx = t - ky * 3;
        short8 ah[ROWS], al[ROWS];
#pragma unroll
        for (int m = 0; m < ROWS; ++m) {
            int p = lyv[ky + m] * AW + lxv[kx];
            int i = (p * 64 + ch * 32 + kg * 8) ^ ((p & 7) << 3);
            ah[m] = *(const short8*)&sAhi[i];
            al[m] = *(const short8*)&sAlo[i];
        }
        const unsigned short* wb = &sW[k & 1][0];
#pragma unroll
        for (int n = 0; n < 4; ++n) {
            short8 bh = *(const short8*)&wb[(n * 64 + lane) * 8];
            short8 bl = *(const short8*)&wb[2048 + (n * 64 + lane) * 8];
#pragma unroll
            for (int m = 0; m < ROWS; ++m) {
                acc[m][n] = __builtin_amdgcn_mfma_f32_16x16x32_bf16(ah[m], bh, acc[m][n], 0, 0, 0);
                acc[m][n] = __builtin_amdgcn_mfma_f32_16x16x32_bf16(ah[m], bl, acc[m][n], 0, 0, 0);
                acc[m][n] = __builtin_amdgcn_mfma_f32_16x16x32_bf16(al[m], bh, acc[m][n], 0, 0, 0);
            }
        }
        __syncthreads();
    }

    if (NHWC_OUT) {
        const int opitch = H + 2;
#pragma unroll
        for (int n = 0; n < 4; ++n) {
            int co = n * 16 + lc;
            float bv = bias[co];
#pragma unroll
            for (int m = 0; m < ROWS; ++m) {
                int row = y0 + ROWS * wv + m, cb = x0 + kg * 4;
                f32x4 v = acc[m][n];
#pragma unroll
                for (int j = 0; j < 4; ++j) {
                    float val = fmaxf(v[j] + bv, 0.f);
                    unsigned short h, l;
                    bf16split(val, h, l);
                    size_t a = ((size_t)(b * opitch + row + 1) * opitch + cb + j + 1) * 64 + co;
                    ohi[a] = h; olo[a] = l;
                }
            }
        }
    } else {
#pragma unroll
        for (int n = 0; n < 4; ++n) {
            int co = n * 16 + lc;
            float bv = bias[co];
#pragma unroll
            for (int m = 0; m < ROWS; ++m) {
                int row = y0 + ROWS * wv + m, cb = x0 + kg * 4;
                f32x4 v = acc[m][n], res;
                res.x = fmaxf(v.x + bv, 0.f);
                res.y = fmaxf(v.y + bv, 0.f);
                res.z = fmaxf(v.z + bv, 0.f);
                res.w = fmaxf(v.w + bv, 0.f);
                *(f32x4*)&outf[((size_t)(b * 64 + co) * H + row) * H + cb] = res;
            }
        }
    }
}

__global__ __launch_bounds__(256, 2) void conv1_mfma_kernel(
    const unsigned short* __restrict__ ahi, const unsigned short* __restrict__ alo,
    const unsigned short* __restrict__ whiP, const unsigned short* __restrict__ wloP,
    const float* __restrict__ bias, float* __restrict__ outf)
{ conv_mfma_body<0, 32, 2, false>(ahi, alo, whiP, wloP, bias, outf, nullptr, nullptr); }

__global__ __launch_bounds__(256, 3) void conv3_mfma_kernel(
    const unsigned short* __restrict__ ahi, const unsigned short* __restrict__ alo,
    const unsigned short* __restrict__ whiP, const unsigned short* __restrict__ wloP,
    const float* __restrict__ bias,
    unsigned short* __restrict__ ohi, unsigned short* __restrict__ olo)
{ conv_mfma_body<1, 32, 2, true>(ahi, alo, whiP, wloP, bias, nullptr, ohi, olo); }

__global__ __launch_bounds__(256, 3) void conv4_mfma_kernel(
    const unsigned short* __restrict__ ahi, const unsigned short* __restrict__ alo,
    const unsigned short* __restrict__ whiP, const unsigned short* __restrict__ wloP,
    const float* __restrict__ bias, float* __restrict__ outf)
{ conv_mfma_body<1, 64, 4, false>(ahi, alo, whiP, wloP, bias, outf, nullptr, nullptr); }

// ---- fused NTM chain: pool+enc+LSTM+gamma+ntmout+conv2, 1 block = 1 image ----
__global__ __launch_bounds__(1024) void ntm_chain_kernel(
    const float* __restrict__ t1, const float* __restrict__ w_enc,
    const float* __restrict__ b_enc, const float* __restrict__ wx,
    const float* __restrict__ bl, const float* __restrict__ w_param,
    const float* __restrict__ b_param, const float* __restrict__ w_out,
    const float* __restrict__ b_out, const double* __restrict__ rsP,
    const float* __restrict__ w2, const float* __restrict__ b2,
    unsigned short* __restrict__ ohi, unsigned short* __restrict__ olo)
{
    int b = blockIdx.x, t = threadIdx.x;
    __shared__ float  sE[16384];       // pooled (64,16,16)
    __shared__ float  eP[4][256];      // enc partials
    __shared__ float  sx[256];         // enc out
    __shared__ float  zbuf[3][256];    // lstm gate pre-activations
    __shared__ float  sh[256];         // h
    __shared__ double red[3][256];     // gamma reduce
    __shared__ double srv[3];          // read-value scalars
    __shared__ float  dP[4][256];      // ntmout dot partials
    __shared__ float  sNtm[256];       // ntm out image

    // --- pool: t1 (b,64,32,32) -> sE (64,16,16) ---
#pragma unroll
    for (int p = t; p < 16384; p += 1024) {
        int ch = p >> 8, y = (p >> 4) & 15, x = p & 15;
        const float* ip = t1 + ((size_t)(b * 64 + ch) * 32 + 2 * y) * 32 + 2 * x;
        sE[p] = (ip[0] + ip[1] + ip[32] + ip[33]) * 0.25f;
    }
    __syncthreads();
    // --- enc: 4 ci-groups of 16 channels each ---
    {
        int g = t >> 8, j = t & 255;
        int y = j >> 4, x = j & 15;
        float a0 = 0.f, a1 = 0.f;
        for (int cc = 0; cc < 16; ++cc) {
            int ci = g * 16 + cc;
#pragma unroll
            for (int ky = 0; ky < 3; ++ky) {
                int gy = y + ky - 1;
                if ((unsigned)gy >= 16u) continue;
#pragma unroll
                for (int kx = 0; kx < 3; ++kx) {
                    int gx = x + kx - 1;
                    if ((unsigned)gx >= 16u) continue;
                    float pr = w_enc[ci * 9 + ky * 3 + kx] * sE[ci * 256 + gy * 16 + gx];
                    if (cc & 1) a1 += pr; else a0 += pr;
                }
            }
        }
        eP[g][j] = a0 + a1;
    }
    __syncthreads();
    if (t < 256) {
        float v = ((eP[0][t] + eP[1][t]) + (eP[2][t] + eP[3][t])) + b_enc[0];
        sx[t] = fmaxf(v, 0.f);
    }
    __syncthreads();
    // --- lstm z-GEMM: threads 0..767, thread = (gate, column), 8-acc fp32 ---
    if (t < 768) {
        int g = t >> 8, j = t & 255;
        int off = (g == 0) ? 0 : (g == 1 ? 512 : 768);
        const float* wp = wx + off + j;
        float acc[8];
#pragma unroll
        for (int k = 0; k < 8; ++k) acc[k] = 0.f;
        for (int d0 = 0; d0 < 256; d0 += 8) {
            float xv[8], wv[8];
#pragma unroll
            for (int k = 0; k < 8; ++k) xv[k] = sx[d0 + k];
#pragma unroll
            for (int k = 0; k < 8; ++k) wv[k] = wp[(size_t)(d0 + k) * 1024];
#pragma unroll
            for (int k = 0; k < 8; ++k) acc[k] = fmaf(xv[k], wv[k], acc[k]);
        }
        zbuf[g][j] = ((acc[0] + acc[1]) + (acc[2] + acc[3]))
                   + ((acc[4] + acc[5]) + (acc[6] + acc[7]));
    }
    __syncthreads();
    if (t < 256) {                                     // gates + h
        int j = t;
        float zif = (float)((double)zbuf[0][j] + (double)bl[j]);
        float zgf = (float)((double)zbuf[1][j] + (double)bl[512 + j]);
        float zof = (float)((double)zbuf[2][j] + (double)bl[768 + j]);
        double c = (1.0 / (1.0 + exp(-(double)zif))) * tanh((double)zgf);
        float cf = (float)c;
        double hh = (1.0 / (1.0 + exp(-(double)zof))) * tanh((double)cf);
        sh[j] = (float)hh;
    }
    __syncthreads();
    // --- gamma: products then LDS tree reduce ---
    if (t < 768) {
        int r = t >> 8, j = t & 255;
        red[r][j] = (double)sh[j] * (double)w_param[(size_t)j * 3108 + r * 262 + 261];
    }
    __syncthreads();
    for (int s = 128; s > 0; s >>= 1) {
        if (t < 768) {
            int r = t >> 8, j = t & 255;
            if (j < s) red[r][j] += red[r][j + s];
        }
        __syncthreads();
    }
    if (t < 3) {
        double s = red[t][0];
        float pf = (float)(s + (double)b_param[t * 262 + 261]);
        pf = fminf(fmaxf(pf, -20.f), 20.f);
        double gamma = log1p(exp((double)pf)) + 1.0;
        double q = pow(0.015625 + 1e-16, gamma);
        double wv = q / (64.0 * q + 1e-8);
        srv[t] = wv * 64.0 * 1e-6;
    }
    __syncthreads();
    // --- ntmout dot: thread (q, m), quarter-dots of 64 terms, 4-acc fp32 ---
    {
        int q = t >> 8, m = t & 255;
        const float* wp = w_out + (size_t)(q * 64) * 256 + m;
        float a4[4] = {0.f, 0.f, 0.f, 0.f};
        for (int d0 = 0; d0 < 64; d0 += 4) {
            float hv4[4], wv4[4];
#pragma unroll
            for (int k = 0; k < 4; ++k) hv4[k] = sh[q * 64 + d0 + k];
#pragma unroll
            for (int k = 0; k < 4; ++k) wv4[k] = wp[(size_t)(d0 + k) * 256];
#pragma unroll
            for (int k = 0; k < 4; ++k) a4[k] = fmaf(hv4[k], wv4[k], a4[k]);
        }
        dP[q][m] = (a4[0] + a4[1]) + (a4[2] + a4[3]);
    }
    __syncthreads();
    if (t < 256) {
        int m = t;
        float dotf = (dP[0][m] + dP[1][m]) + (dP[2][m] + dP[3][m]);
        double acc = (double)dotf + (double)b_out[m];
#pragma unroll
        for (int r = 0; r < 3; ++r) {
            double rsum = 0;
#pragma unroll
            for (int c = 0; c < 8; ++c) rsum += rsP[((r * 8 + c) << 8) + m];
            acc += srv[r] * rsum;
        }
        acc = fmin(fmax(acc, -20.0), 20.0);
        sNtm[m] = (float)acc;
    }
    __syncthreads();
    // --- conv2: 1->64 3x3 SAME + relu -> A3 NHWC hi/lo ---
    for (int p = t; p < 16384; p += 1024) {
        int co = p & 63, x4 = (p >> 6) & 15, y4 = p >> 10;
        float a = b2[co];
#pragma unroll
        for (int ky = 0; ky < 3; ++ky) {
            int gy = y4 + ky - 1;
            if ((unsigned)gy >= 16u) continue;
#pragma unroll
            for (int kx = 0; kx < 3; ++kx) {
                int gx = x4 + kx - 1;
                if ((unsigned)gx >= 16u) continue;
                a = fmaf(w2[co * 9 + ky * 3 + kx], sNtm[gy * 16 + gx], a);
            }
        }
        unsigned short hh, ll;
        bf16split(fmaxf(a, 0.f), hh, ll);
        size_t adst = ((size_t)(b * 18 + y4 + 1) * 18 + x4 + 1) * 64 + co;
        ohi[adst] = hh; olo[adst] = ll;
    }
}

extern "C" void kernel_launch(void* const* d_in, const int* in_sizes, int n_in,
                              void* d_out, int out_size, void* d_ws, size_t ws_size,
                              hipStream_t stream)
{
    const float* inputs   = (const float*)d_in[0];
    const float* w_conv0  = (const float*)d_in[1];
    const float* b_conv0  = (const float*)d_in[2];
    const float* w_conv1  = (const float*)d_in[3];
    const float* b_conv1  = (const float*)d_in[4];
    const float* w_enc    = (const float*)d_in[5];
    const float* b_enc    = (const float*)d_in[6];
    const float* w_conv2  = (const float*)d_in[7];
    const float* b_conv2  = (const float*)d_in[8];
    const float* w_conv3  = (const float*)d_in[9];
    const float* b_conv3  = (const float*)d_in[10];
    const float* w_conv4  = (const float*)d_in[11];
    const float* b_conv4  = (const float*)d_in[12];
    const float* w_lstm_x = (const float*)d_in[13];
    // d_in[14] = w_lstm_h : dead (h0 == 0)
    const float* b_lstm   = (const float*)d_in[15];
    const float* w_param  = (const float*)d_in[16];
    const float* b_param  = (const float*)d_in[17];
    const float* w_out_   = (const float*)d_in[18];
    const float* b_out_   = (const float*)d_in[19];

    char* ws = (char*)d_ws;
    unsigned short* a1h = (unsigned short*)(ws + OFF_A1H);
    unsigned short* a1l = (unsigned short*)(ws + OFF_A1L);
    float*  t1  = (float*)(ws + OFF_T1);
    unsigned short* a3h = (unsigned short*)(ws + OFF_A3H);
    unsigned short* a3l = (unsigned short*)(ws + OFF_A3L);
    unsigned short* a4h = a1h;                         // A4 reuses A1
    unsigned short* a4l = a1l;
    unsigned short* whi1 = (unsigned short*)(ws + OFF_W1); unsigned short* wlo1 = whi1 + 36864;
    unsigned short* whi3 = (unsigned short*)(ws + OFF_W3); unsigned short* wlo3 = whi3 + 36864;
    unsigned short* whi4 = (unsigned short*)(ws + OFF_W4); unsigned short* wlo4 = whi4 + 36864;
    double* rsP = (double*)(ws + OFF_RS);

    wprep_rowsum_kernel<<<456, 256, 0, stream>>>(
        w_conv1, w_conv3, w_conv4, w_out_,
        whi1, wlo1, whi3, wlo3, whi4, wlo4, rsP);
    halo_all_kernel<<<3200, 256, 0, stream>>>(a1h, a1l, a3h, a3l);

    conv0_pool_kernel<<<16384, 256, 0, stream>>>(inputs, w_conv0, b_conv0, a1h, a1l);
    conv1_mfma_kernel<<<512, 256, 0, stream>>>(a1h, a1l, whi1, wlo1, b_conv1, t1);

    ntm_chain_kernel<<<64, 1024, 0, stream>>>(
        t1, w_enc, b_enc, w_lstm_x, b_lstm, w_param, b_param,
        w_out_, b_out_, rsP, w_conv2, b_conv2, a3h, a3l);

    conv3_mfma_kernel<<<512, 256, 0, stream>>>(a3h, a3l, whi3, wlo3, b_conv3, a4h, a4l);
    conv4_mfma_kernel<<<1024, 256, 0, stream>>>(a4h, a4l, whi4, wlo4, b_conv4, (float*)d_out);
}

// Round 13
// 205.311 us; speedup vs baseline: 1.4997x; 1.0197x over previous
//
#include <hip/hip_runtime.h>
#include <hip/hip_bf16.h>

// ============================================================================
// Round 13: kill the t1 round-trip. R12's ntm_chain = 88us with FETCH 19MB —
// dominated by the 16MB t1 (conv1 NCHW out) read by only 64 blocks at ~200GB/s
// latency-bound. conv1's ROWS=2 epilogue already holds each 2x2 pool cell
// in-register (wave owns rows {2wv,2wv+1}, lane holds 4 consecutive x), so
// conv1 now applies bias+relu+avgpool in the epilogue and writes only the
// pooled (64,64,16,16) f32 = 4MB. ntm_chain's pool phase becomes a coalesced
// 64KB/block LDS copy. Pool math reassociation-only (~1e-7 vs 3.8e-6 floor).
// Everything else identical to r12.
// ============================================================================

typedef __attribute__((ext_vector_type(8))) short short8;
typedef __attribute__((ext_vector_type(4))) float f32x4;

// ---- workspace layout (bytes) ----
static const size_t OFF_A1H = 0;                       // A1/A4 NHWC hi (B,34,34,64)
static const size_t OFF_A1L = 9469952;                 // -> end 18,939,904
static const size_t OFF_PL  = 18939904;                // pooled (64,64,16,16) f32 4MB
static const size_t OFF_A3H = 39911424;                // conv3 input NHWC (B,18,18,64)
static const size_t OFF_A3L = 42565632;                // -> end 45,219,840
static const size_t OFF_W1  = 45219840;                // packed whi+wlo 147,456 B/layer
static const size_t OFF_W3  = 45367296;
static const size_t OFF_W4  = 45514752;
static const size_t OFF_RS  = 45662208;                // rs_part (24,256) f64 49,152B

__device__ inline void bf16split(float v, unsigned short& h, unsigned short& l) {
    __hip_bfloat16 hb = __float2bfloat16(v);
    float hf = __bfloat162float(hb);
    __hip_bfloat16 lb = __float2bfloat16(v - hf);
    h = __builtin_bit_cast(unsigned short, hb);
    l = __builtin_bit_cast(unsigned short, lb);
}

// ---- prep: weight fragment-pack (blocks 0..431) + rowsum partials (432..455)
__global__ void wprep_rowsum_kernel(
    const float* __restrict__ w1, const float* __restrict__ w3,
    const float* __restrict__ w4, const float* __restrict__ w_out,
    unsigned short* __restrict__ whi1, unsigned short* __restrict__ wlo1,
    unsigned short* __restrict__ whi3, unsigned short* __restrict__ wlo3,
    unsigned short* __restrict__ whi4, unsigned short* __restrict__ wlo4,
    double* __restrict__ rsP)
{
    int blk = blockIdx.x;
    if (blk >= 432) {                                  // rowsum partials
        int idx = blk - 432;                           // 0..23
        int r = idx >> 3, c = idx & 7;
        int m = threadIdx.x;
        const float* wp = w_out + (size_t)(256 + r * 256 + c * 32) * 256 + m;
        double s[4] = {0, 0, 0, 0};
        for (int d0 = 0; d0 < 32; d0 += 4) {
#pragma unroll
            for (int k = 0; k < 4; ++k)
                s[k] += (double)wp[(size_t)(d0 + k) * 256];
        }
        rsP[(idx << 8) + m] = (s[0] + s[1]) + (s[2] + s[3]);
        return;
    }
    int layer = blk / 144;
    int r = (blk % 144) * 256 + threadIdx.x;           // < 36864
    const float* w = layer == 0 ? w1 : (layer == 1 ? w3 : w4);
    unsigned short* hi = layer == 0 ? whi1 : (layer == 1 ? whi3 : whi4);
    unsigned short* lo = layer == 0 ? wlo1 : (layer == 1 ? wlo3 : wlo4);
    int j  = r & 7;
    int ln = (r >> 3) & 63;
    int n  = (r >> 9) & 3;
    int ch = (r >> 11) & 1;
    int t  = r >> 12;
    int lc = ln & 15, kg = ln >> 4;
    int co = n * 16 + lc;
    int ci = ch * 32 + kg * 8 + j;
    unsigned short h, l;
    bf16split(w[(co * 64 + ci) * 9 + t], h, l);
    hi[r] = h; lo[r] = l;
}

// ---- zero halo rings of a1 (S=32) and a3 (S=16) in one kernel ----
__device__ inline void halo_zero_one(unsigned short* hi, unsigned short* lo,
                                     int S, int idx)
{
    int P = S + 2, ring = 4 * S + 4;
    int co = idx & 63;
    int cell = (idx >> 6) % ring;
    int b = (idx >> 6) / ring;
    int y, x;
    if (cell < P)            { y = 0;     x = cell; }
    else if (cell < 2 * P)   { y = P - 1; x = cell - P; }
    else { int c2 = cell - 2 * P; y = 1 + (c2 >> 1); x = (c2 & 1) ? P - 1 : 0; }
    size_t a = ((size_t)(b * P + y) * P + x) * 64 + co;
    hi[a] = 0; lo[a] = 0;
}

__global__ void halo_all_kernel(unsigned short* __restrict__ a1h,
                                unsigned short* __restrict__ a1l,
                                unsigned short* __restrict__ a3h,
                                unsigned short* __restrict__ a3l)
{
    int idx = blockIdx.x * 256 + threadIdx.x;          // 819,200 total
    if (idx < 540672) halo_zero_one(a1h, a1l, 32, idx);
    else              halo_zero_one(a3h, a3l, 16, idx - 540672);
}

// ---- fused conv0 (1->64, 3x3 SAME, relu) + avgpool2 -> A1 NHWC hi/lo ----
__global__ __launch_bounds__(256) void conv0_pool_kernel(
    const float* __restrict__ in, const float* __restrict__ w,
    const float* __restrict__ bias,
    unsigned short* __restrict__ ohi, unsigned short* __restrict__ olo)
{
    int idx = blockIdx.x * 256 + threadIdx.x;          // 4,194,304
    int co = idx & 63, x = (idx >> 6) & 31, y = (idx >> 11) & 31, b = idx >> 16;
    float w9[9];
#pragma unroll
    for (int t = 0; t < 9; ++t) w9[t] = w[co * 9 + t];
    float bv = bias[co];
    const float* ip = in + (size_t)b * 4096;
    float p[4][4];
#pragma unroll
    for (int r = 0; r < 4; ++r) {
        int gy = 2 * y - 1 + r;
#pragma unroll
        for (int c = 0; c < 4; ++c) {
            int gx = 2 * x - 1 + c;
            float v = 0.f;
            if ((unsigned)gy < 64u && (unsigned)gx < 64u) v = ip[gy * 64 + gx];
            p[r][c] = v;
        }
    }
    float s4 = 0.f;
#pragma unroll
    for (int dy = 0; dy < 2; ++dy)
#pragma unroll
        for (int dx = 0; dx < 2; ++dx) {
            float a = bv;
#pragma unroll
            for (int ky = 0; ky < 3; ++ky)
#pragma unroll
                for (int kx = 0; kx < 3; ++kx)
                    a = fmaf(w9[ky * 3 + kx], p[dy + ky][dx + kx], a);
            s4 += fmaxf(a, 0.f);
        }
    unsigned short h, l;
    bf16split(s4 * 0.25f, h, l);
    size_t a = ((size_t)(b * 34 + y + 1) * 34 + x + 1) * 64 + co;
    ohi[a] = h; olo[a] = l;
}

// ---- MFMA implicit-GEMM conv body: 256 thr / 4 waves, ROWS rows per wave ----
// OUT mode: 0 = NCHW f32, 1 = NHWC bf16 hi/lo (next conv input), 2 = fused
// bias+relu+avgpool2 -> pooled NCHW f32 (requires ROWS==2).
template <int UP, int H, int ROWS, int OUTMODE>
__device__ __forceinline__ void conv_mfma_body(
    const unsigned short* __restrict__ ahi, const unsigned short* __restrict__ alo,
    const unsigned short* __restrict__ whiP, const unsigned short* __restrict__ wloP,
    const float* __restrict__ bias,
    float* __restrict__ outf, unsigned short* __restrict__ ohi,
    unsigned short* __restrict__ olo)
{
    constexpr int TILEH = 4 * ROWS;
    constexpr int SRC   = H >> UP;
    constexpr int PITCH = SRC + 2;
    constexpr int TPR   = H / 16;
    constexpr int TPC   = H / TILEH;
    constexpr int AH    = (UP ? TILEH / 2 : TILEH) + 2;
    constexpr int AW    = UP ? 10 : 18;
    constexpr int NPX   = AH * AW;

    int b  = blockIdx.x / (TPC * TPR);
    int tt = blockIdx.x % (TPC * TPR);
    int y0 = (tt / TPR) * TILEH, x0 = (tt % TPR) * 16;
    const int tid = threadIdx.x;
    const int wv = tid >> 6, lane = tid & 63;
    const int lc = lane & 15, kg = lane >> 4;

    __shared__ unsigned short sAhi[NPX * 64];
    __shared__ unsigned short sAlo[NPX * 64];
    __shared__ unsigned short sW[2][4096];             // [buf][hi 2048 | lo 2048]

    const int r0 = ((y0 - 1) >> UP) + 1;
    const int c0 = ((x0 - 1) >> UP) + 1;

    for (int c = tid; c < NPX * 8; c += 256) {
        int pix = c >> 3, sub = c & 7;
        int py = pix / AW, px = pix - py * AW;
        size_t g = ((size_t)(b * PITCH + r0 + py) * PITCH + (c0 + px)) * 64 + sub * 8;
        int l = (pix * 64 + sub * 8) ^ ((pix & 7) << 3);
        *(short8*)&sAhi[l] = *(const short8*)&ahi[g];
        *(short8*)&sAlo[l] = *(const short8*)&alo[g];
    }
    for (int c = tid; c < 512; c += 256) {
        if (c < 256) *(short8*)&sW[0][c * 8] = *(const short8*)&whiP[c * 8];
        else *(short8*)&sW[0][2048 + (c - 256) * 8] = *(const short8*)&wloP[(c - 256) * 8];
    }
    __syncthreads();

    int lxv[3], lyv[ROWS + 2];
#pragma unroll
    for (int kx = 0; kx < 3; ++kx)
        lxv[kx] = (((x0 + lc + kx - 1) >> UP) + 1) - c0;
#pragma unroll
    for (int r = 0; r < ROWS + 2; ++r)
        lyv[r] = (((y0 + ROWS * wv + r - 1) >> UP) + 1) - r0;

    f32x4 acc[ROWS][4];
#pragma unroll
    for (int m = 0; m < ROWS; ++m)
#pragma unroll
        for (int n = 0; n < 4; ++n) acc[m][n] = f32x4{0.f, 0.f, 0.f, 0.f};

#pragma unroll
    for (int k = 0; k < 18; ++k) {                     // k = t*2 + ch
        if (k + 1 < 18) {                              // prefetch next W slice
            int slb = (k + 1) * 2048;
            for (int c = tid; c < 512; c += 256) {
                if (c < 256) *(short8*)&sW[(k + 1) & 1][c * 8] =
                    *(const short8*)&whiP[slb + c * 8];
                else *(short8*)&sW[(k + 1) & 1][2048 + (c - 256) * 8] =
                    *(const short8*)&wloP[slb + (c - 256) * 8];
            }
        }
        const int t = k >> 1, ch = k & 1;
        const int ky = t / 3, kx = t - ky * 3;
        short8 ah[ROWS], al[ROWS];
#pragma unroll
        for (int m = 0; m < ROWS; ++m) {
            int p = lyv[ky + m] * AW + lxv[kx];
            int i = (p * 64 + ch * 32 + kg * 8) ^ ((p & 7) << 3);
            ah[m] = *(const short8*)&sAhi[i];
            al[m] = *(const short8*)&sAlo[i];
        }
        const unsigned short* wb = &sW[k & 1][0];
#pragma unroll
        for (int n = 0; n < 4; ++n) {
            short8 bh = *(const short8*)&wb[(n * 64 + lane) * 8];
            short8 bl = *(const short8*)&wb[2048 + (n * 64 + lane) * 8];
#pragma unroll
            for (int m = 0; m < ROWS; ++m) {
                acc[m][n] = __builtin_amdgcn_mfma_f32_16x16x32_bf16(ah[m], bh, acc[m][n], 0, 0, 0);
                acc[m][n] = __builtin_amdgcn_mfma_f32_16x16x32_bf16(ah[m], bl, acc[m][n], 0, 0, 0);
                acc[m][n] = __builtin_amdgcn_mfma_f32_16x16x32_bf16(al[m], bh, acc[m][n], 0, 0, 0);
            }
        }
        __syncthreads();
    }

    // epilogue: D col(lane&15)=co frag idx, row(kg*4+reg)=pixel-x (verified r4)
    if (OUTMODE == 1) {
        const int opitch = H + 2;
#pragma unroll
        for (int n = 0; n < 4; ++n) {
            int co = n * 16 + lc;
            float bv = bias[co];
#pragma unroll
            for (int m = 0; m < ROWS; ++m) {
                int row = y0 + ROWS * wv + m, cb = x0 + kg * 4;
                f32x4 v = acc[m][n];
#pragma unroll
                for (int j = 0; j < 4; ++j) {
                    float val = fmaxf(v[j] + bv, 0.f);
                    unsigned short h, l;
                    bf16split(val, h, l);
                    size_t a = ((size_t)(b * opitch + row + 1) * opitch + cb + j + 1) * 64 + co;
                    ohi[a] = h; olo[a] = l;
                }
            }
        }
    } else if (OUTMODE == 2) {                         // fused relu+avgpool2 (ROWS==2)
#pragma unroll
        for (int n = 0; n < 4; ++n) {
            int co = n * 16 + lc;
            float bv = bias[co];
            f32x4 v0 = acc[0][n], v1 = acc[1][n];
            float r00 = fmaxf(v0.x + bv, 0.f), r01 = fmaxf(v0.y + bv, 0.f);
            float r02 = fmaxf(v0.z + bv, 0.f), r03 = fmaxf(v0.w + bv, 0.f);
            float r10 = fmaxf(v1.x + bv, 0.f), r11 = fmaxf(v1.y + bv, 0.f);
            float r12 = fmaxf(v1.z + bv, 0.f), r13 = fmaxf(v1.w + bv, 0.f);
            float p0 = ((r00 + r01) + (r10 + r11)) * 0.25f;
            float p1 = ((r02 + r03) + (r12 + r13)) * 0.25f;
            int py = (y0 >> 1) + wv;                   // pooled row
            int px = (x0 >> 1) + kg * 2;               // pooled col base
            float* op = outf + ((size_t)(b * 64 + co) * 16 + py) * 16 + px;
            op[0] = p0; op[1] = p1;
        }
    } else {
#pragma unroll
        for (int n = 0; n < 4; ++n) {
            int co = n * 16 + lc;
            float bv = bias[co];
#pragma unroll
            for (int m = 0; m < ROWS; ++m) {
                int row = y0 + ROWS * wv + m, cb = x0 + kg * 4;
                f32x4 v = acc[m][n], res;
                res.x = fmaxf(v.x + bv, 0.f);
                res.y = fmaxf(v.y + bv, 0.f);
                res.z = fmaxf(v.z + bv, 0.f);
                res.w = fmaxf(v.w + bv, 0.f);
                *(f32x4*)&outf[((size_t)(b * 64 + co) * H + row) * H + cb] = res;
            }
        }
    }
}

__global__ __launch_bounds__(256, 2) void conv1_mfma_kernel(
    const unsigned short* __restrict__ ahi, const unsigned short* __restrict__ alo,
    const unsigned short* __restrict__ whiP, const unsigned short* __restrict__ wloP,
    const float* __restrict__ bias, float* __restrict__ pooled)
{ conv_mfma_body<0, 32, 2, 2>(ahi, alo, whiP, wloP, bias, pooled, nullptr, nullptr); }

__global__ __launch_bounds__(256, 3) void conv3_mfma_kernel(
    const unsigned short* __restrict__ ahi, const unsigned short* __restrict__ alo,
    const unsigned short* __restrict__ whiP, const unsigned short* __restrict__ wloP,
    const float* __restrict__ bias,
    unsigned short* __restrict__ ohi, unsigned short* __restrict__ olo)
{ conv_mfma_body<1, 32, 2, 1>(ahi, alo, whiP, wloP, bias, nullptr, ohi, olo); }

__global__ __launch_bounds__(256, 3) void conv4_mfma_kernel(
    const unsigned short* __restrict__ ahi, const unsigned short* __restrict__ alo,
    const unsigned short* __restrict__ whiP, const unsigned short* __restrict__ wloP,
    const float* __restrict__ bias, float* __restrict__ outf)
{ conv_mfma_body<1, 64, 4, 0>(ahi, alo, whiP, wloP, bias, outf, nullptr, nullptr); }

// ---- fused NTM chain: enc+LSTM+gamma+ntmout+conv2, 1 block = 1 image ----
// (pool now fused into conv1; pooled (64,64,16,16) f32 loaded straight to LDS)
__global__ __launch_bounds__(1024) void ntm_chain_kernel(
    const float* __restrict__ pooled, const float* __restrict__ w_enc,
    const float* __restrict__ b_enc, const float* __restrict__ wx,
    const float* __restrict__ bl, const float* __restrict__ w_param,
    const float* __restrict__ b_param, const float* __restrict__ w_out,
    const float* __restrict__ b_out, const double* __restrict__ rsP,
    const float* __restrict__ w2, const float* __restrict__ b2,
    unsigned short* __restrict__ ohi, unsigned short* __restrict__ olo)
{
    int b = blockIdx.x, t = threadIdx.x;
    __shared__ float  sE[16384];       // pooled (64,16,16)
    __shared__ float  eP[4][256];      // enc partials
    __shared__ float  sx[256];         // enc out
    __shared__ float  zbuf[3][256];    // lstm gate pre-activations
    __shared__ float  sh[256];         // h
    __shared__ double red[3][256];     // gamma reduce
    __shared__ double srv[3];          // read-value scalars
    __shared__ float  dP[4][256];      // ntmout dot partials
    __shared__ float  sNtm[256];       // ntm out image

    // --- load pooled image (coalesced float4, 64KB) ---
    {
        const f32x4* src = (const f32x4*)(pooled + (size_t)b * 16384);
        f32x4* dst = (f32x4*)sE;
#pragma unroll
        for (int p = t; p < 4096; p += 1024) dst[p] = src[p];
    }
    __syncthreads();
    // --- enc: 4 ci-groups of 16 channels each ---
    {
        int g = t >> 8, j = t & 255;
        int y = j >> 4, x = j & 15;
        float a0 = 0.f, a1 = 0.f;
        for (int cc = 0; cc < 16; ++cc) {
            int ci = g * 16 + cc;
#pragma unroll
            for (int ky = 0; ky < 3; ++ky) {
                int gy = y + ky - 1;
                if ((unsigned)gy >= 16u) continue;
#pragma unroll
                for (int kx = 0; kx < 3; ++kx) {
                    int gx = x + kx - 1;
                    if ((unsigned)gx >= 16u) continue;
                    float pr = w_enc[ci * 9 + ky * 3 + kx] * sE[ci * 256 + gy * 16 + gx];
                    if (cc & 1) a1 += pr; else a0 += pr;
                }
            }
        }
        eP[g][j] = a0 + a1;
    }
    __syncthreads();
    if (t < 256) {
        float v = ((eP[0][t] + eP[1][t]) + (eP[2][t] + eP[3][t])) + b_enc[0];
        sx[t] = fmaxf(v, 0.f);
    }
    __syncthreads();
    // --- lstm z-GEMM: threads 0..767, thread = (gate, column), 8-acc fp32 ---
    if (t < 768) {
        int g = t >> 8, j = t & 255;
        int off = (g == 0) ? 0 : (g == 1 ? 512 : 768);
        const float* wp = wx + off + j;
        float acc[8];
#pragma unroll
        for (int k = 0; k < 8; ++k) acc[k] = 0.f;
        for (int d0 = 0; d0 < 256; d0 += 8) {
            float xv[8], wv[8];
#pragma unroll
            for (int k = 0; k < 8; ++k) xv[k] = sx[d0 + k];
#pragma unroll
            for (int k = 0; k < 8; ++k) wv[k] = wp[(size_t)(d0 + k) * 1024];
#pragma unroll
            for (int k = 0; k < 8; ++k) acc[k] = fmaf(xv[k], wv[k], acc[k]);
        }
        zbuf[g][j] = ((acc[0] + acc[1]) + (acc[2] + acc[3]))
                   + ((acc[4] + acc[5]) + (acc[6] + acc[7]));
    }
    __syncthreads();
    if (t < 256) {                                     // gates + h
        int j = t;
        float zif = (float)((double)zbuf[0][j] + (double)bl[j]);
        float zgf = (float)((double)zbuf[1][j] + (double)bl[512 + j]);
        float zof = (float)((double)zbuf[2][j] + (double)bl[768 + j]);
        double c = (1.0 / (1.0 + exp(-(double)zif))) * tanh((double)zgf);
        float cf = (float)c;
        double hh = (1.0 / (1.0 + exp(-(double)zof))) * tanh((double)cf);
        sh[j] = (float)hh;
    }
    __syncthreads();
    // --- gamma: products then LDS tree reduce ---
    if (t < 768) {
        int r = t >> 8, j = t & 255;
        red[r][j] = (double)sh[j] * (double)w_param[(size_t)j * 3108 + r * 262 + 261];
    }
    __syncthreads();
    for (int s = 128; s > 0; s >>= 1) {
        if (t < 768) {
            int r = t >> 8, j = t & 255;
            if (j < s) red[r][j] += red[r][j + s];
        }
        __syncthreads();
    }
    if (t < 3) {
        double s = red[t][0];
        float pf = (float)(s + (double)b_param[t * 262 + 261]);
        pf = fminf(fmaxf(pf, -20.f), 20.f);
        double gamma = log1p(exp((double)pf)) + 1.0;
        double q = pow(0.015625 + 1e-16, gamma);
        double wv = q / (64.0 * q + 1e-8);
        srv[t] = wv * 64.0 * 1e-6;
    }
    __syncthreads();
    // --- ntmout dot: thread (q, m), quarter-dots of 64 terms, 4-acc fp32 ---
    {
        int q = t >> 8, m = t & 255;
        const float* wp = w_out + (size_t)(q * 64) * 256 + m;
        float a4[4] = {0.f, 0.f, 0.f, 0.f};
        for (int d0 = 0; d0 < 64; d0 += 4) {
            float hv4[4], wv4[4];
#pragma unroll
            for (int k = 0; k < 4; ++k) hv4[k] = sh[q * 64 + d0 + k];
#pragma unroll
            for (int k = 0; k < 4; ++k) wv4[k] = wp[(size_t)(d0 + k) * 256];
#pragma unroll
            for (int k = 0; k < 4; ++k) a4[k] = fmaf(hv4[k], wv4[k], a4[k]);
        }
        dP[q][m] = (a4[0] + a4[1]) + (a4[2] + a4[3]);
    }
    __syncthreads();
    if (t < 256) {
        int m = t;
        float dotf = (dP[0][m] + dP[1][m]) + (dP[2][m] + dP[3][m]);
        double acc = (double)dotf + (double)b_out[m];
#pragma unroll
        for (int r = 0; r < 3; ++r) {
            double rsum = 0;
#pragma unroll
            for (int c = 0; c < 8; ++c) rsum += rsP[((r * 8 + c) << 8) + m];
            acc += srv[r] * rsum;
        }
        acc = fmin(fmax(acc, -20.0), 20.0);
        sNtm[m] = (float)acc;
    }
    __syncthreads();
    // --- conv2: 1->64 3x3 SAME + relu -> A3 NHWC hi/lo ---
    for (int p = t; p < 16384; p += 1024) {
        int co = p & 63, x4 = (p >> 6) & 15, y4 = p >> 10;
        float a = b2[co];
#pragma unroll
        for (int ky = 0; ky < 3; ++ky) {
            int gy = y4 + ky - 1;
            if ((unsigned)gy >= 16u) continue;
#pragma unroll
            for (int kx = 0; kx < 3; ++kx) {
                int gx = x4 + kx - 1;
                if ((unsigned)gx >= 16u) continue;
                a = fmaf(w2[co * 9 + ky * 3 + kx], sNtm[gy * 16 + gx], a);
            }
        }
        unsigned short hh, ll;
        bf16split(fmaxf(a, 0.f), hh, ll);
        size_t adst = ((size_t)(b * 18 + y4 + 1) * 18 + x4 + 1) * 64 + co;
        ohi[adst] = hh; olo[adst] = ll;
    }
}

extern "C" void kernel_launch(void* const* d_in, const int* in_sizes, int n_in,
                              void* d_out, int out_size, void* d_ws, size_t ws_size,
                              hipStream_t stream)
{
    const float* inputs   = (const float*)d_in[0];
    const float* w_conv0  = (const float*)d_in[1];
    const float* b_conv0  = (const float*)d_in[2];
    const float* w_conv1  = (const float*)d_in[3];
    const float* b_conv1  = (const float*)d_in[4];
    const float* w_enc    = (const float*)d_in[5];
    const float* b_enc    = (const float*)d_in[6];
    const float* w_conv2  = (const float*)d_in[7];
    const float* b_conv2  = (const float*)d_in[8];
    const float* w_conv3  = (const float*)d_in[9];
    const float* b_conv3  = (const float*)d_in[10];
    const float* w_conv4  = (const float*)d_in[11];
    const float* b_conv4  = (const float*)d_in[12];
    const float* w_lstm_x = (const float*)d_in[13];
    // d_in[14] = w_lstm_h : dead (h0 == 0)
    const float* b_lstm   = (const float*)d_in[15];
    const float* w_param  = (const float*)d_in[16];
    const float* b_param  = (const float*)d_in[17];
    const float* w_out_   = (const float*)d_in[18];
    const float* b_out_   = (const float*)d_in[19];

    char* ws = (char*)d_ws;
    unsigned short* a1h = (unsigned short*)(ws + OFF_A1H);
    unsigned short* a1l = (unsigned short*)(ws + OFF_A1L);
    float*  pooled = (float*)(ws + OFF_PL);
    unsigned short* a3h = (unsigned short*)(ws + OFF_A3H);
    unsigned short* a3l = (unsigned short*)(ws + OFF_A3L);
    unsigned short* a4h = a1h;                         // A4 reuses A1
    unsigned short* a4l = a1l;
    unsigned short* whi1 = (unsigned short*)(ws + OFF_W1); unsigned short* wlo1 = whi1 + 36864;
    unsigned short* whi3 = (unsigned short*)(ws + OFF_W3); unsigned short* wlo3 = whi3 + 36864;
    unsigned short* whi4 = (unsigned short*)(ws + OFF_W4); unsigned short* wlo4 = whi4 + 36864;
    double* rsP = (double*)(ws + OFF_RS);

    wprep_rowsum_kernel<<<456, 256, 0, stream>>>(
        w_conv1, w_conv3, w_conv4, w_out_,
        whi1, wlo1, whi3, wlo3, whi4, wlo4, rsP);
    halo_all_kernel<<<3200, 256, 0, stream>>>(a1h, a1l, a3h, a3l);

    conv0_pool_kernel<<<16384, 256, 0, stream>>>(inputs, w_conv0, b_conv0, a1h, a1l);
    conv1_mfma_kernel<<<512, 256, 0, stream>>>(a1h, a1l, whi1, wlo1, b_conv1, pooled);

    ntm_chain_kernel<<<64, 1024, 0, stream>>>(
        pooled, w_enc, b_enc, w_lstm_x, b_lstm, w_param, b_param,
        w_out_, b_out_, rsP, w_conv2, b_conv2, a3h, a3l);

    conv3_mfma_kernel<<<512, 256, 0, stream>>>(a3h, a3l, whi3, wlo3, b_conv3, a4h, a4l);
    conv4_mfma_kernel<<<1024, 256, 0, stream>>>(a4h, a4l, whi4, wlo4, b_conv4, (float*)d_out);
}